// Round 14
// baseline (540.281 us; speedup 1.0000x reference)
//
#include <hip/hip_runtime.h>
#include <hip/hip_bf16.h>
#include <hip/hip_cooperative_groups.h>

namespace cg = cooperative_groups;

typedef __attribute__((ext_vector_type(8))) short short8;
typedef __attribute__((ext_vector_type(4))) float f32x4;

__device__ __forceinline__ unsigned bf16u(float x) {
    unsigned u = __float_as_uint(x);
    return (u + 0x7fffu + ((u >> 16) & 1u)) >> 16;
}
__device__ __forceinline__ short bf16s(float x) { return (short)bf16u(x); }

// ---------------------------------------------------------------------------
// Cooperative build kernel: weight prep + CSR build + node_up in ONE launch.
// Phases separated by grid.sync(). Grid = 512 x 256 (co-resident on 256 CUs).
//   A: zero cnt; pack W1B/Wm2B/W3B (MLP) and WoB (epilogue) B-fragments
//   B: histogram of receivers
//   C: scan (block-local 256-wide -> block-0 scans partials -> add base)
//   D: fill_pack (per-edge basis/meta records into CSR slots)
//   E: node_up (u bf16x4 packed + xpk)
// ---------------------------------------------------------------------------
__global__ __launch_bounds__(256) void build_kernel(
    const float* __restrict__ vectors, const float* __restrict__ node_feats,
    const int* __restrict__ senders, const int* __restrict__ receivers,
    const float* __restrict__ W0_up, const float* __restrict__ W1_up,
    const float* __restrict__ Wm1, const float* __restrict__ Wm2,
    const float* __restrict__ Wm3,
    const float* __restrict__ Wd0, const float* __restrict__ Ws0,
    const float* __restrict__ Wd1, const float* __restrict__ Ws1,
    int* __restrict__ cnt, int* __restrict__ offs, int* __restrict__ cursor,
    int* __restrict__ part,
    uint4* __restrict__ epackA, float4* __restrict__ epackB,
    uint2* __restrict__ ubf, short* __restrict__ xpk,
    short* __restrict__ W1B, short* __restrict__ Wm2B, short* __restrict__ W3B,
    short* __restrict__ WoB, int N, int E)
{
    cg::grid_group grid = cg::this_grid();
    __shared__ int sA[256], sB[256];
    const int t = threadIdx.x;
    const int tid = blockIdx.x * 256 + t;
    const int nth = gridDim.x * 256;
    const int nseg = (N + 255) >> 8;

    // ---- phase A: zero cnt + weight packing ----
    for (int i = tid; i < N; i += nth) cnt[i] = 0;
    for (int idx = tid; idx < 52 * 64; idx += nth) {
        int l = idx & 63, f = idx >> 6;
        int g = l >> 4, c = l & 15;
        short8 v;
        if (f < 4) {
            #pragma unroll
            for (int i = 0; i < 8; ++i)
                v[i] = (g == 0) ? bf16s(Wm1[(size_t)i * 64 + f * 16 + c]) : (short)0;
            *(short8*)(W1B + (size_t)f * 512 + l * 8) = v;
        } else if (f < 12) {
            int f2 = f - 4, tt = f2 >> 1, kh = f2 & 1;
            #pragma unroll
            for (int i = 0; i < 8; ++i)
                v[i] = bf16s(Wm2[(size_t)(kh * 32 + g * 8 + i) * 64 + tt * 16 + c]);
            *(short8*)(Wm2B + (size_t)f2 * 512 + l * 8) = v;
        } else {
            int f3 = f - 12, tt = f3 >> 1, kh = f3 & 1;
            #pragma unroll
            for (int i = 0; i < 8; ++i)
                v[i] = bf16s(Wm3[(size_t)(kh * 32 + g * 8 + i) * 320 + tt * 16 + c]);
            *(short8*)(W3B + (size_t)f3 * 512 + l * 8) = v;
        }
    }
    for (int idx = tid; idx < 144 * 64; idx += nth) {
        int l = idx & 63, f = idx >> 6;
        int g = l >> 4, c = l & 15;
        short8 v;
        if (f < 16) {
            int tt = f >> 1, kh = f & 1;
            #pragma unroll
            for (int i = 0; i < 8; ++i)
                v[i] = bf16s(Wd0[(size_t)(kh * 32 + g * 8 + i) * 128 + tt * 16 + c]);
        } else if (f < 96) {
            int s = (f - 16) >> 4, r = (f - 16) & 15, tt = r >> 1, kh = r & 1;
            #pragma unroll
            for (int i = 0; i < 8; ++i)
                v[i] = bf16s(Ws0[((size_t)s * 64 + kh * 32 + g * 8 + i) * 128 + tt * 16 + c]);
        } else if (f < 104) {
            int r = f - 96, tt = r >> 1, kh = r & 1;
            #pragma unroll
            for (int i = 0; i < 8; ++i)
                v[i] = bf16s(Wd1[(size_t)(kh * 32 + g * 8 + i) * 64 + tt * 16 + c]);
        } else {
            int s = (f - 104) >> 3, r = (f - 104) & 7, tt = r >> 1, kh = r & 1;
            #pragma unroll
            for (int i = 0; i < 8; ++i)
                v[i] = bf16s(Ws1[((size_t)s * 64 + kh * 32 + g * 8 + i) * 64 + tt * 16 + c]);
        }
        *(short8*)(WoB + (size_t)f * 512 + l * 8) = v;
    }
    grid.sync();

    // ---- phase B: histogram ----
    for (int i = tid; i < E; i += nth) atomicAdd(&cnt[receivers[i]], 1);
    grid.sync();

    // ---- phase C1: block-local scan (1 elem/thread, 256/segment) ----
    for (int seg = blockIdx.x; seg < nseg; seg += gridDim.x) {
        int i = seg * 256 + t;
        int v = (i < N) ? cnt[i] : 0;
        sA[t] = v;
        __syncthreads();
        int* src = sA; int* dst = sB;
        for (int off = 1; off < 256; off <<= 1) {
            dst[t] = src[t] + ((t >= off) ? src[t - off] : 0);
            __syncthreads();
            int* tmp = src; src = dst; dst = tmp;
        }
        int incl = src[t];
        if (i < N) offs[i] = incl - v;          // local exclusive
        if (t == 255) part[seg] = incl;          // segment total
        __syncthreads();
    }
    grid.sync();

    // ---- phase C2: block 0 scans segment totals (nseg <= 256) ----
    if (blockIdx.x == 0) {
        int v = (t < nseg) ? part[t] : 0;
        sA[t] = v;
        __syncthreads();
        int* src = sA; int* dst = sB;
        for (int off = 1; off < 256; off <<= 1) {
            dst[t] = src[t] + ((t >= off) ? src[t - off] : 0);
            __syncthreads();
            int* tmp = src; src = dst; dst = tmp;
        }
        int incl = src[t];
        if (t < nseg) part[t] = incl - v;        // exclusive base
        if (t == 255) offs[N] = incl;            // grand total
    }
    grid.sync();

    // ---- phase C3: add base, mirror into cursor ----
    for (int i = tid; i < N; i += nth) {
        int o = offs[i] + part[i >> 8];
        offs[i] = o;
        cursor[i] = o;
    }
    grid.sync();

    // ---- phase D: fill_pack ----
    for (int i = tid; i < E; i += nth) {
        int pos = atomicAdd(&cursor[receivers[i]], 1);
        float vx = vectors[3 * (size_t)i + 0];
        float vy = vectors[3 * (size_t)i + 1];
        float vz = vectors[3 * (size_t)i + 2];
        float r = sqrtf(vx * vx + vy * vy + vz * vz);
        float ir = (r != 0.f) ? 1.f / r : 0.f;
        float ang = r * 0.6283185307179586f;   // pi/5
        float s1, c1;
        __sincosf(ang, &s1, &c1);
        float tc = 2.f * c1;
        float sb = s1, sp = 0.f;
        float coef = 0.6324555320336759f * ir;
        unsigned bw[4];
        #pragma unroll
        for (int h = 0; h < 4; ++h) {
            unsigned lo = bf16u(sb * coef);
            float nx = tc * sb - sp; sp = sb; sb = nx;
            unsigned hi = bf16u(sb * coef);
            nx = tc * sb - sp; sp = sb; sb = nx;
            bw[h] = lo | (hi << 16);
        }
        epackA[pos] = make_uint4(bw[0], bw[1], bw[2], bw[3]);
        epackB[pos] = make_float4(vx * ir, vy * ir, vz * ir,
                                  __int_as_float(senders[i]));
    }

    // ---- phase E: node_up (independent of D; no sync needed) ----
    for (int i = tid; i < N * 64; i += nth) {
        int nb = i >> 6, d = i & 63;
        const float* nf = node_feats + (size_t)nb * 256;
        float a0 = 0.f, ax = 0.f, ay = 0.f, az = 0.f;
        #pragma unroll 4
        for (int cc = 0; cc < 64; ++cc) {
            float w0 = W0_up[cc * 64 + d];
            float w1 = W1_up[cc * 64 + d];
            a0 += nf[cc] * w0;
            ax += nf[64 + cc * 3 + 0] * w1;
            ay += nf[64 + cc * 3 + 1] * w1;
            az += nf[64 + cc * 3 + 2] * w1;
        }
        ubf[(size_t)nb * 64 + d] = make_uint2(bf16u(a0) | (bf16u(ax) << 16),
                                              bf16u(ay) | (bf16u(az) << 16));
        short* xp = xpk + (size_t)nb * 256;
        xp[d]       = bf16s(nf[d]);
        xp[64 + d]  = bf16s(nf[64 + d * 3 + 0]);
        xp[128 + d] = bf16s(nf[64 + d * 3 + 1]);
        xp[192 + d] = bf16s(nf[64 + d * 3 + 2]);
    }
}

// ---------------------------------------------------------------------------
// Edge kernel v10: PERSISTENT wave-per-node, 16-edge MFMA chunks. (unchanged)
// ---------------------------------------------------------------------------
__global__ __launch_bounds__(256) void edge_kernel(
    const uint4* __restrict__ epackA, const float4* __restrict__ epackB,
    const int* __restrict__ offs, const uint2* __restrict__ ubf,
    const short* __restrict__ W1B, const short* __restrict__ Wm2B,
    const short* __restrict__ W3B, float* __restrict__ acc,
    int N, int nwaves)
{
    __shared__ __align__(16) short ldsW3[40 * 512];   // 40KB staged W3B
    __shared__ __align__(16) short ldsH[4][1024];     // per-wave h buffer (swz)
    __shared__ __align__(16) float ldsMeta[4][16][4]; // Y.xyz + sender

    {   // cooperative stage of W3B (2560 short8), once per block
        const short8* src = (const short8*)W3B;
        short8* dst = (short8*)ldsW3;
        for (int i = threadIdx.x; i < 2560; i += 256) dst[i] = src[i];
    }
    __syncthreads();

    const int lane = threadIdx.x & 63;
    const int wv   = threadIdx.x >> 6;
    const int gw   = blockIdx.x * 4 + wv;
    const int c = lane & 15, g = lane >> 4;

    for (int n = gw; n < N; n += nwaves) {

        float a0q[4]  = {0.f, 0.f, 0.f, 0.f};
        float a1xq[4] = {0.f, 0.f, 0.f, 0.f};
        float a1yq[4] = {0.f, 0.f, 0.f, 0.f};
        float a1zq[4] = {0.f, 0.f, 0.f, 0.f};

        const int beg = offs[n], end = offs[n + 1];

        for (int p0 = beg; p0 < end; p0 += 16) {
            const int m = end - p0;

            short8 basisA = {0, 0, 0, 0, 0, 0, 0, 0};
            if (lane < 16) {
                uint4 ba = epackA[p0 + lane];
                float4 mb = epackB[p0 + lane];
                if (lane >= m) {
                    ba = make_uint4(0u, 0u, 0u, 0u);
                    mb = make_float4(0.f, 0.f, 0.f, __int_as_float(0));
                }
                union { uint4 u4v; short8 s8; } cv;
                cv.u4v = ba;
                basisA = cv.s8;
                *(float4*)&ldsMeta[wv][lane][0] = mb;
            }

            float Yx[4], Yy[4], Yz[4];
            int snd[4];
            #pragma unroll
            for (int i = 0; i < 4; ++i) {
                int row = 4 * g + i;
                float4 mt = *(const float4*)&ldsMeta[wv][row][0];
                Yx[i] = mt.x; Yy[i] = mt.y; Yz[i] = mt.z;
                snd[i] = __float_as_int(mt.w);
            }

#define PFETCH(Q, MV)                                                       \
            _Pragma("unroll")                                               \
            for (int i = 0; i < 4; ++i)                                     \
                MV[i] = ubf[(size_t)snd[i] * 64 + 16 * (Q) + c];

#define COMPQ(Q, MV)                                                        \
        {                                                                   \
            float M0[4], M1X[4], M1Y[4], M1Z[4];                            \
            _Pragma("unroll")                                               \
            for (int i = 0; i < 4; ++i) {                                   \
                M0[i]  = __uint_as_float(MV[i].x << 16);                    \
                M1X[i] = __uint_as_float(MV[i].x & 0xffff0000u);            \
                M1Y[i] = __uint_as_float(MV[i].y << 16);                    \
                M1Z[i] = __uint_as_float(MV[i].y & 0xffff0000u);            \
            }                                                               \
            _Pragma("unroll")                                               \
            for (int p = 0; p < 5; ++p) {                                   \
                const int t = 4 * p + (Q);                                  \
                f32x4 w = {0.f, 0.f, 0.f, 0.f};                             \
                short8 b0 = *(const short8*)(ldsW3 + (size_t)(t * 2) * 512 + lane * 8);     \
                short8 b1 = *(const short8*)(ldsW3 + (size_t)(t * 2 + 1) * 512 + lane * 8); \
                w = __builtin_amdgcn_mfma_f32_16x16x32_bf16(h2f0, b0, w, 0, 0, 0);          \
                w = __builtin_amdgcn_mfma_f32_16x16x32_bf16(h2f1, b1, w, 0, 0, 0);          \
                _Pragma("unroll")                                           \
                for (int i = 0; i < 4; ++i) {                               \
                    float wv_ = w[i];                                       \
                    if (p == 0) {                                           \
                        a0q[Q] += wv_ * M0[i];                              \
                    } else if (p == 1) {                                    \
                        float tt = wv_ * M0[i];                             \
                        a1xq[Q] += tt * Yx[i];                              \
                        a1yq[Q] += tt * Yy[i];                              \
                        a1zq[Q] += tt * Yz[i];                              \
                    } else if (p == 2) {                                    \
                        a1xq[Q] += wv_ * M1X[i];                            \
                        a1yq[Q] += wv_ * M1Y[i];                            \
                        a1zq[Q] += wv_ * M1Z[i];                            \
                    } else if (p == 3) {                                    \
                        a0q[Q] += wv_ * (M1X[i] * Yx[i] + M1Y[i] * Yy[i] + M1Z[i] * Yz[i]); \
                    } else {                                                \
                        a1xq[Q] += wv_ * (M1Y[i] * Yz[i] - M1Z[i] * Yy[i]); \
                        a1yq[Q] += wv_ * (M1Z[i] * Yx[i] - M1X[i] * Yz[i]); \
                        a1zq[Q] += wv_ * (M1X[i] * Yy[i] - M1Y[i] * Yx[i]); \
                    }                                                       \
                }                                                           \
            }                                                               \
        }

            uint2 mA[4], mB[4];
            PFETCH(0, mA);
            PFETCH(1, mB);
            __builtin_amdgcn_sched_barrier(0);   // keep gathers issued here

            // ---- layer 1: 4 MFMAs; silu -> ldsH (swizzled bf16) ----
            #pragma unroll
            for (int t = 0; t < 4; ++t) {
                f32x4 h = {0.f, 0.f, 0.f, 0.f};
                short8 bf = *(const short8*)(W1B + (size_t)t * 512 + lane * 8);
                h = __builtin_amdgcn_mfma_f32_16x16x32_bf16(basisA, bf, h, 0, 0, 0);
                #pragma unroll
                for (int i = 0; i < 4; ++i) {
                    float x = h[i];
                    float h1 = x / (1.f + __expf(-x));
                    int row = 4 * g + i;
                    ldsH[wv][row * 64 + ((16 * t + c) ^ ((row & 7) << 3))] = bf16s(h1);
                }
            }
            short8 h1f0 = *(const short8*)&ldsH[wv][c * 64 + ((g * 8) ^ ((c & 7) << 3))];
            short8 h1f1 = *(const short8*)&ldsH[wv][c * 64 + ((32 + g * 8) ^ ((c & 7) << 3))];

            // ---- layer 2: 8 MFMAs; silu -> ldsH (reuse) ----
            #pragma unroll
            for (int t = 0; t < 4; ++t) {
                f32x4 h = {0.f, 0.f, 0.f, 0.f};
                short8 b0 = *(const short8*)(Wm2B + (size_t)(t * 2) * 512 + lane * 8);
                short8 b1 = *(const short8*)(Wm2B + (size_t)(t * 2 + 1) * 512 + lane * 8);
                h = __builtin_amdgcn_mfma_f32_16x16x32_bf16(h1f0, b0, h, 0, 0, 0);
                h = __builtin_amdgcn_mfma_f32_16x16x32_bf16(h1f1, b1, h, 0, 0, 0);
                #pragma unroll
                for (int i = 0; i < 4; ++i) {
                    float x = h[i];
                    float h2 = x / (1.f + __expf(-x));
                    int row = 4 * g + i;
                    ldsH[wv][row * 64 + ((16 * t + c) ^ ((row & 7) << 3))] = bf16s(h2);
                }
            }
            short8 h2f0 = *(const short8*)&ldsH[wv][c * 64 + ((g * 8) ^ ((c & 7) << 3))];
            short8 h2f1 = *(const short8*)&ldsH[wv][c * 64 + ((32 + g * 8) ^ ((c & 7) << 3))];

            // ---- layer 3 + fused messages, ping-pong pipelined over q ----
            COMPQ(0, mA);
            __builtin_amdgcn_sched_barrier(0);
            PFETCH(2, mA);
            COMPQ(1, mB);
            __builtin_amdgcn_sched_barrier(0);
            PFETCH(3, mB);
            COMPQ(2, mA);
            __builtin_amdgcn_sched_barrier(0);
            COMPQ(3, mB);
#undef PFETCH
#undef COMPQ
        }

        #pragma unroll
        for (int q = 0; q < 4; ++q) {
            a0q[q]  += __shfl_xor(a0q[q], 16);  a0q[q]  += __shfl_xor(a0q[q], 32);
            a1xq[q] += __shfl_xor(a1xq[q], 16); a1xq[q] += __shfl_xor(a1xq[q], 32);
            a1yq[q] += __shfl_xor(a1yq[q], 16); a1yq[q] += __shfl_xor(a1yq[q], 32);
            a1zq[q] += __shfl_xor(a1zq[q], 16); a1zq[q] += __shfl_xor(a1zq[q], 32);
        }
        if (lane < 16) {
            float* ar = acc + (size_t)n * 256;
            #pragma unroll
            for (int q = 0; q < 4; ++q) {
                ar[16 * q + lane]       = a0q[q];
                ar[64 + 16 * q + lane]  = a1xq[q];
                ar[128 + 16 * q + lane] = a1yq[q];
                ar[192 + 16 * q + lane] = a1zq[q];
            }
        }
    }
}

// ---------------------------------------------------------------------------
// Node epilogue v2: MFMA masked-species dense GEMM. (unchanged)
// ---------------------------------------------------------------------------
__global__ __launch_bounds__(256) void node_out_kernel(
    const float* __restrict__ acc, const short* __restrict__ xpk,
    const int* __restrict__ node_specie, const short* __restrict__ WoB,
    float* __restrict__ out, int N)
{
    __shared__ float ldsOut[4][16][256];   // 64KB
    const int lane = threadIdx.x & 63;
    const int wv   = threadIdx.x >> 6;
    const int c = lane & 15, g = lane >> 4;
    const int n0 = (blockIdx.x * 4 + wv) * 16;
    if (n0 >= N) return;

    const int nc = min(n0 + c, N - 1);        // this lane's A-row node
    const int sp_c = node_specie[nc];
    const short8 z8 = {0, 0, 0, 0, 0, 0, 0, 0};

    short8 x0f[2], a0hi[2], a0lo[2];
    #pragma unroll
    for (int kh = 0; kh < 2; ++kh) {
        x0f[kh] = *(const short8*)&xpk[(size_t)nc * 256 + kh * 32 + g * 8];
        const float* ap = acc + (size_t)nc * 256 + kh * 32 + g * 8;
        #pragma unroll
        for (int i = 0; i < 8; ++i) {
            float v = 0.25f * ap[i];
            unsigned h = bf16u(v);
            a0hi[kh][i] = (short)h;
            a0lo[kh][i] = (short)bf16u(v - __uint_as_float(h << 16));
        }
    }

    f32x4 w0[8];
    #pragma unroll
    for (int t = 0; t < 8; ++t) w0[t] = (f32x4){0.f, 0.f, 0.f, 0.f};
    #pragma unroll
    for (int t = 0; t < 8; ++t)
        #pragma unroll
        for (int kh = 0; kh < 2; ++kh) {
            short8 b = *(const short8*)(WoB + (size_t)(t * 2 + kh) * 512 + lane * 8);
            w0[t] = __builtin_amdgcn_mfma_f32_16x16x32_bf16(a0hi[kh], b, w0[t], 0, 0, 0);
            w0[t] = __builtin_amdgcn_mfma_f32_16x16x32_bf16(a0lo[kh], b, w0[t], 0, 0, 0);
        }
    #pragma unroll
    for (int s = 0; s < 5; ++s) {
        if (!__any(sp_c == s)) continue;
        short8 mk0 = (sp_c == s) ? x0f[0] : z8;
        short8 mk1 = (sp_c == s) ? x0f[1] : z8;
        #pragma unroll
        for (int t = 0; t < 8; ++t) {
            short8 b0 = *(const short8*)(WoB + (size_t)(16 + s * 16 + t * 2) * 512 + lane * 8);
            short8 b1 = *(const short8*)(WoB + (size_t)(16 + s * 16 + t * 2 + 1) * 512 + lane * 8);
            w0[t] = __builtin_amdgcn_mfma_f32_16x16x32_bf16(mk0, b0, w0[t], 0, 0, 0);
            w0[t] = __builtin_amdgcn_mfma_f32_16x16x32_bf16(mk1, b1, w0[t], 0, 0, 0);
        }
    }
    float gate[4][4];
    #pragma unroll
    for (int t = 0; t < 8; ++t)
        #pragma unroll
        for (int i = 0; i < 4; ++i) {
            float x = w0[t][i];
            float sv = x / (1.f + __expf(-x));
            if (t < 4) ldsOut[wv][4 * g + i][16 * t + c] = sv;
            else       gate[t - 4][i] = sv;
        }

    short8 x1f[3][2], a1hi[3][2], a1lo[3][2];
    #pragma unroll
    for (int j = 0; j < 3; ++j)
        #pragma unroll
        for (int kh = 0; kh < 2; ++kh) {
            x1f[j][kh] = *(const short8*)&xpk[(size_t)nc * 256 + (1 + j) * 64 + kh * 32 + g * 8];
            const float* ap = acc + (size_t)nc * 256 + 64 + 64 * j + kh * 32 + g * 8;
            #pragma unroll
            for (int i = 0; i < 8; ++i) {
                float v = 0.25f * ap[i];
                unsigned h = bf16u(v);
                a1hi[j][kh][i] = (short)h;
                a1lo[j][kh][i] = (short)bf16u(v - __uint_as_float(h << 16));
            }
        }

    f32x4 w1[3][4];
    #pragma unroll
    for (int j = 0; j < 3; ++j)
        #pragma unroll
        for (int t = 0; t < 4; ++t) w1[j][t] = (f32x4){0.f, 0.f, 0.f, 0.f};
    #pragma unroll
    for (int t = 0; t < 4; ++t)
        #pragma unroll
        for (int kh = 0; kh < 2; ++kh) {
            short8 b = *(const short8*)(WoB + (size_t)(96 + t * 2 + kh) * 512 + lane * 8);
            #pragma unroll
            for (int j = 0; j < 3; ++j) {
                w1[j][t] = __builtin_amdgcn_mfma_f32_16x16x32_bf16(a1hi[j][kh], b, w1[j][t], 0, 0, 0);
                w1[j][t] = __builtin_amdgcn_mfma_f32_16x16x32_bf16(a1lo[j][kh], b, w1[j][t], 0, 0, 0);
            }
        }
    #pragma unroll
    for (int s = 0; s < 5; ++s) {
        if (!__any(sp_c == s)) continue;
        short8 m1[3][2];
        #pragma unroll
        for (int j = 0; j < 3; ++j) {
            m1[j][0] = (sp_c == s) ? x1f[j][0] : z8;
            m1[j][1] = (sp_c == s) ? x1f[j][1] : z8;
        }
        #pragma unroll
        for (int t = 0; t < 4; ++t)
            #pragma unroll
            for (int kh = 0; kh < 2; ++kh) {
                short8 b = *(const short8*)(WoB + (size_t)(104 + s * 8 + t * 2 + kh) * 512 + lane * 8);
                #pragma unroll
                for (int j = 0; j < 3; ++j)
                    w1[j][t] = __builtin_amdgcn_mfma_f32_16x16x32_bf16(m1[j][kh], b, w1[j][t], 0, 0, 0);
            }
    }
    #pragma unroll
    for (int j = 0; j < 3; ++j)
        #pragma unroll
        for (int t = 0; t < 4; ++t)
            #pragma unroll
            for (int i = 0; i < 4; ++i)
                ldsOut[wv][4 * g + i][64 + (16 * t + c) * 3 + j] = w1[j][t][i] * gate[t][i];

    #pragma unroll 4
    for (int r = 0; r < 16; ++r) {
        int nn = n0 + r;
        if (nn < N)
            *(float4*)&out[(size_t)nn * 256 + lane * 4] =
                *(const float4*)&ldsOut[wv][r][lane * 4];
    }
}

// ---------------------------------------------------------------------------
extern "C" void kernel_launch(void* const* d_in, const int* in_sizes, int n_in,
                              void* d_out, int out_size, void* d_ws, size_t ws_size,
                              hipStream_t stream) {
    const float* vectors     = (const float*)d_in[0];
    const float* node_feats  = (const float*)d_in[1];
    const int*   node_specie = (const int*)d_in[2];
    const int*   senders     = (const int*)d_in[3];
    const int*   receivers   = (const int*)d_in[4];
    const float* W0_up       = (const float*)d_in[5];
    const float* W1_up       = (const float*)d_in[6];
    const float* Wm1         = (const float*)d_in[7];
    const float* Wm2         = (const float*)d_in[8];
    const float* Wm3         = (const float*)d_in[9];
    const float* Ws0         = (const float*)d_in[10];
    const float* Ws1         = (const float*)d_in[11];
    const float* Wd0         = (const float*)d_in[12];
    const float* Wd1         = (const float*)d_in[13];
    float* out = (float*)d_out;

    int E = in_sizes[0] / 3;
    int N = in_sizes[1] / 256;

    char* wp = (char*)d_ws;
    uint2* ubf    = (uint2*)wp;                 wp += (size_t)N * 64 * 8;
    float* acc    = (float*)wp;                 wp += (size_t)N * 256 * 4;
    short* xpk    = (short*)wp;                 wp += (size_t)N * 256 * 2;
    uint4* epackA = (uint4*)wp;                 wp += (size_t)(E + 16) * 16;
    float4* epackB = (float4*)wp;               wp += (size_t)(E + 16) * 16;
    short* W1B    = (short*)wp;                 wp += 4 * 512 * 2;
    short* Wm2B   = (short*)wp;                 wp += 8 * 512 * 2;
    short* W3B    = (short*)wp;                 wp += 40 * 512 * 2;
    short* WoB    = (short*)wp;                 wp += 144 * 512 * 2;
    int*   cnt    = (int*)wp;                   wp += (size_t)N * 4;
    int*   offs   = (int*)wp;                   wp += (size_t)(N + 1) * 4;
    int*   cursor = (int*)wp;                   wp += (size_t)N * 4;
    int*   part   = (int*)wp;                   wp += (size_t)512 * 4;

    // ---- single cooperative launch: prep + CSR + node_up ----
    void* args[] = {
        (void*)&vectors, (void*)&node_feats, (void*)&senders, (void*)&receivers,
        (void*)&W0_up, (void*)&W1_up, (void*)&Wm1, (void*)&Wm2, (void*)&Wm3,
        (void*)&Wd0, (void*)&Ws0, (void*)&Wd1, (void*)&Ws1,
        (void*)&cnt, (void*)&offs, (void*)&cursor, (void*)&part,
        (void*)&epackA, (void*)&epackB, (void*)&ubf, (void*)&xpk,
        (void*)&W1B, (void*)&Wm2B, (void*)&W3B, (void*)&WoB,
        (void*)&N, (void*)&E
    };
    hipLaunchCooperativeKernel((const void*)build_kernel, dim3(512), dim3(256),
                               args, 0, stream);

    const int EDGE_BLOCKS = 512;
    edge_kernel<<<EDGE_BLOCKS, 256, 0, stream>>>(
        epackA, epackB, offs, ubf, W1B, Wm2B, W3B, acc, N, EDGE_BLOCKS * 4);
    int ngroups = (N + 15) / 16;
    node_out_kernel<<<(ngroups + 3) / 4, 256, 0, stream>>>(
        acc, xpk, node_specie, WoB, out, N);
}

// Round 15
// 283.430 us; speedup vs baseline: 1.9062x; 1.9062x over previous
//
#include <hip/hip_runtime.h>
#include <hip/hip_bf16.h>

typedef __attribute__((ext_vector_type(8))) short short8;
typedef __attribute__((ext_vector_type(4))) float f32x4;

__device__ __forceinline__ unsigned bf16u(float x) {
    unsigned u = __float_as_uint(x);
    return (u + 0x7fffu + ((u >> 16) & 1u)) >> 16;
}
__device__ __forceinline__ short bf16s(float x) { return (short)bf16u(x); }

// ---------------------------------------------------------------------------
// Prep (merged): zero cnt + pack ALL weights into MFMA B-fragments.
//  MLP:      W1B 4 | Wm2B 8 | W3B 40 frags
//  Epilogue: WoB = [Wd0 16 | Ws0 5x16 | Wd1 8 | Ws1 5x8] = 144 frags
// Frag (t,kh): lane l holds B[k=kh*32+(l>>4)*8+i][col=16t+(l&15)].
// ---------------------------------------------------------------------------
__global__ __launch_bounds__(256) void prep_kernel(
    const float* __restrict__ Wm1, const float* __restrict__ Wm2,
    const float* __restrict__ Wm3,
    const float* __restrict__ Wd0, const float* __restrict__ Ws0,
    const float* __restrict__ Wd1, const float* __restrict__ Ws1,
    short* __restrict__ W1B, short* __restrict__ Wm2B, short* __restrict__ W3B,
    short* __restrict__ WoB, int* __restrict__ cnt, int N)
{
    const int tid = blockIdx.x * 256 + threadIdx.x;
    const int nth = gridDim.x * 256;

    for (int i = tid; i < N; i += nth) cnt[i] = 0;

    for (int idx = tid; idx < 52 * 64; idx += nth) {
        int l = idx & 63, f = idx >> 6;
        int g = l >> 4, c = l & 15;
        short8 v;
        if (f < 4) {
            #pragma unroll
            for (int i = 0; i < 8; ++i)
                v[i] = (g == 0) ? bf16s(Wm1[(size_t)i * 64 + f * 16 + c]) : (short)0;
            *(short8*)(W1B + (size_t)f * 512 + l * 8) = v;
        } else if (f < 12) {
            int f2 = f - 4, t = f2 >> 1, kh = f2 & 1;
            #pragma unroll
            for (int i = 0; i < 8; ++i)
                v[i] = bf16s(Wm2[(size_t)(kh * 32 + g * 8 + i) * 64 + t * 16 + c]);
            *(short8*)(Wm2B + (size_t)f2 * 512 + l * 8) = v;
        } else {
            int f3 = f - 12, t = f3 >> 1, kh = f3 & 1;
            #pragma unroll
            for (int i = 0; i < 8; ++i)
                v[i] = bf16s(Wm3[(size_t)(kh * 32 + g * 8 + i) * 320 + t * 16 + c]);
            *(short8*)(W3B + (size_t)f3 * 512 + l * 8) = v;
        }
    }

    for (int idx = tid; idx < 144 * 64; idx += nth) {
        int l = idx & 63, f = idx >> 6;
        int g = l >> 4, c = l & 15;
        short8 v;
        if (f < 16) {
            int t = f >> 1, kh = f & 1;
            #pragma unroll
            for (int i = 0; i < 8; ++i)
                v[i] = bf16s(Wd0[(size_t)(kh * 32 + g * 8 + i) * 128 + t * 16 + c]);
        } else if (f < 96) {
            int s = (f - 16) >> 4, r = (f - 16) & 15, t = r >> 1, kh = r & 1;
            #pragma unroll
            for (int i = 0; i < 8; ++i)
                v[i] = bf16s(Ws0[((size_t)s * 64 + kh * 32 + g * 8 + i) * 128 + t * 16 + c]);
        } else if (f < 104) {
            int r = f - 96, t = r >> 1, kh = r & 1;
            #pragma unroll
            for (int i = 0; i < 8; ++i)
                v[i] = bf16s(Wd1[(size_t)(kh * 32 + g * 8 + i) * 64 + t * 16 + c]);
        } else {
            int s = (f - 104) >> 3, r = (f - 104) & 7, t = r >> 1, kh = r & 1;
            #pragma unroll
            for (int i = 0; i < 8; ++i)
                v[i] = bf16s(Ws1[((size_t)s * 64 + kh * 32 + g * 8 + i) * 64 + t * 16 + c]);
        }
        *(short8*)(WoB + (size_t)f * 512 + l * 8) = v;
    }
}

// ---------------------------------------------------------------------------
// CSR build: histogram -> 3-phase parallel scan -> bucket fill (+ pack)
// ---------------------------------------------------------------------------
__global__ __launch_bounds__(256) void hist_kernel(
    const int* __restrict__ receivers, int* __restrict__ cnt, int E)
{
    int i = blockIdx.x * 256 + threadIdx.x;
    int stride = gridDim.x * 256;
    for (; i < E; i += stride) atomicAdd(&cnt[receivers[i]], 1);
}

__global__ __launch_bounds__(256) void scan1_kernel(
    const int* __restrict__ cnt, int* __restrict__ offs,
    int* __restrict__ part, int N)
{
    __shared__ int a_[256], b_[256];
    const int b = blockIdx.x, t = threadIdx.x;
    const int base = b * 1024 + t * 4;
    int v[4];
    #pragma unroll
    for (int k = 0; k < 4; ++k) v[k] = (base + k < N) ? cnt[base + k] : 0;
    int sum = v[0] + v[1] + v[2] + v[3];
    a_[t] = sum;
    __syncthreads();
    int* src = a_; int* dst = b_;
    for (int off = 1; off < 256; off <<= 1) {
        dst[t] = src[t] + ((t >= off) ? src[t - off] : 0);
        __syncthreads();
        int* tmp = src; src = dst; dst = tmp;
    }
    int excl = src[t] - sum;
    if (t == 0) part[b] = src[255];
    int run = excl;
    #pragma unroll
    for (int k = 0; k < 4; ++k) {
        if (base + k < N) offs[base + k] = run;
        run += v[k];
    }
}

__global__ void scan2_kernel(int* __restrict__ part, int* __restrict__ offs,
                             int nblk, int N)
{
    if (threadIdx.x == 0 && blockIdx.x == 0) {
        int running = 0;
        for (int i = 0; i < nblk; ++i) {
            int tmp = part[i];
            part[i] = running;
            running += tmp;
        }
        offs[N] = running;
    }
}

__global__ __launch_bounds__(256) void scan3_kernel(
    int* __restrict__ offs, int* __restrict__ cursor,
    const int* __restrict__ part, int N)
{
    const int b = blockIdx.x, t = threadIdx.x;
    const int add = part[b];
    const int base = b * 1024 + t * 4;
    #pragma unroll
    for (int k = 0; k < 4; ++k) {
        int i = base + k;
        if (i < N) {
            int o = offs[i] + add;
            offs[i] = o;
            cursor[i] = o;
        }
    }
}

// Scatter per-edge packed record into CSR position.
__global__ __launch_bounds__(256) void fill_pack_kernel(
    const float* __restrict__ vectors, const int* __restrict__ senders,
    const int* __restrict__ receivers, int* __restrict__ cursor,
    uint4* __restrict__ epackA, float4* __restrict__ epackB, int E)
{
    int i = blockIdx.x * 256 + threadIdx.x;
    int stride = gridDim.x * 256;
    for (; i < E; i += stride) {
        int pos = atomicAdd(&cursor[receivers[i]], 1);
        float vx = vectors[3 * (size_t)i + 0];
        float vy = vectors[3 * (size_t)i + 1];
        float vz = vectors[3 * (size_t)i + 2];
        float r = sqrtf(vx * vx + vy * vy + vz * vz);
        float ir = (r != 0.f) ? 1.f / r : 0.f;
        float ang = r * 0.6283185307179586f;   // pi/5
        float s1, c1;
        __sincosf(ang, &s1, &c1);
        float tc = 2.f * c1;
        float sb = s1, sp = 0.f;
        float coef = 0.6324555320336759f * ir;
        unsigned bw[4];
        #pragma unroll
        for (int h = 0; h < 4; ++h) {
            unsigned lo = bf16u(sb * coef);
            float nx = tc * sb - sp; sp = sb; sb = nx;
            unsigned hi = bf16u(sb * coef);
            nx = tc * sb - sp; sp = sb; sb = nx;
            bw[h] = lo | (hi << 16);
        }
        epackA[pos] = make_uint4(bw[0], bw[1], bw[2], bw[3]);
        epackB[pos] = make_float4(vx * ir, vy * ir, vz * ir,
                                  __int_as_float(senders[i]));
    }
}

// ---------------------------------------------------------------------------
// Node up-projection, packed bf16x4 per (node, d) + xpk bf16 node feats.
// ---------------------------------------------------------------------------
__global__ __launch_bounds__(256) void node_up_kernel(
    const float* __restrict__ node_feats, const float* __restrict__ W0_up,
    const float* __restrict__ W1_up, uint2* __restrict__ ubf,
    short* __restrict__ xpk, int N)
{
    int nb = blockIdx.x * 4 + (threadIdx.x >> 6);
    int d  = threadIdx.x & 63;
    if (nb >= N) return;
    const float* nf = node_feats + (size_t)nb * 256;
    float a0 = 0.f, ax = 0.f, ay = 0.f, az = 0.f;
    #pragma unroll 4
    for (int cc = 0; cc < 64; ++cc) {
        float w0 = W0_up[cc * 64 + d];
        float w1 = W1_up[cc * 64 + d];
        a0 += nf[cc] * w0;
        ax += nf[64 + cc * 3 + 0] * w1;
        ay += nf[64 + cc * 3 + 1] * w1;
        az += nf[64 + cc * 3 + 2] * w1;
    }
    ubf[(size_t)nb * 64 + d] = make_uint2(bf16u(a0) | (bf16u(ax) << 16),
                                          bf16u(ay) | (bf16u(az) << 16));
    short* xp = xpk + (size_t)nb * 256;
    xp[d]       = bf16s(nf[d]);
    xp[64 + d]  = bf16s(nf[64 + d * 3 + 0]);
    xp[128 + d] = bf16s(nf[64 + d * 3 + 1]);
    xp[192 + d] = bf16s(nf[64 + d * 3 + 2]);
}

// ---------------------------------------------------------------------------
// Edge kernel v11: persistent wave-per-node, 16-edge MFMA chunks.
//  - VGPR trim: Y.xyz NOT kept live across the chunk; reloaded from per-wave
//    LDS meta inside each COMPQ (frees ~12 regs -> target <=170 for
//    3 waves/SIMD; LDS 50KB allows 3 blocks/CU). Grid 768 = 3 blocks/CU.
//  - plain __launch_bounds__(256): min-waves hints force spills (R5-R9).
// ---------------------------------------------------------------------------
__global__ __launch_bounds__(256) void edge_kernel(
    const uint4* __restrict__ epackA, const float4* __restrict__ epackB,
    const int* __restrict__ offs, const uint2* __restrict__ ubf,
    const short* __restrict__ W1B, const short* __restrict__ Wm2B,
    const short* __restrict__ W3B, float* __restrict__ acc,
    int N, int nwaves)
{
    __shared__ __align__(16) short ldsW3[40 * 512];   // 40KB staged W3B
    __shared__ __align__(16) short ldsH[4][1024];     // per-wave h buffer (swz)
    __shared__ __align__(16) float ldsMeta[4][16][4]; // Y.xyz + sender

    {   // cooperative stage of W3B (2560 short8), once per block
        const short8* src = (const short8*)W3B;
        short8* dst = (short8*)ldsW3;
        for (int i = threadIdx.x; i < 2560; i += 256) dst[i] = src[i];
    }
    __syncthreads();

    const int lane = threadIdx.x & 63;
    const int wv   = threadIdx.x >> 6;
    const int gw   = blockIdx.x * 4 + wv;
    const int c = lane & 15, g = lane >> 4;

    for (int n = gw; n < N; n += nwaves) {

        float a0q[4]  = {0.f, 0.f, 0.f, 0.f};
        float a1xq[4] = {0.f, 0.f, 0.f, 0.f};
        float a1yq[4] = {0.f, 0.f, 0.f, 0.f};
        float a1zq[4] = {0.f, 0.f, 0.f, 0.f};

        const int beg = offs[n], end = offs[n + 1];

        for (int p0 = beg; p0 < end; p0 += 16) {
            const int m = end - p0;

            short8 basisA = {0, 0, 0, 0, 0, 0, 0, 0};
            if (lane < 16) {
                uint4 ba = epackA[p0 + lane];
                float4 mb = epackB[p0 + lane];
                if (lane >= m) {
                    ba = make_uint4(0u, 0u, 0u, 0u);
                    mb = make_float4(0.f, 0.f, 0.f, __int_as_float(0));
                }
                union { uint4 u4v; short8 s8; } cv;
                cv.u4v = ba;
                basisA = cv.s8;
                *(float4*)&ldsMeta[wv][lane][0] = mb;
            }

            // only sender indices stay live across the chunk (4 regs)
            int snd[4];
            #pragma unroll
            for (int i = 0; i < 4; ++i)
                snd[i] = __float_as_int(ldsMeta[wv][4 * g + i][3]);

#define PFETCH(Q, MV)                                                       \
            _Pragma("unroll")                                               \
            for (int i = 0; i < 4; ++i)                                     \
                MV[i] = ubf[(size_t)snd[i] * 64 + 16 * (Q) + c];

#define COMPQ(Q, MV)                                                        \
        {                                                                   \
            float M0[4], M1X[4], M1Y[4], M1Z[4];                            \
            float Yx_[4], Yy_[4], Yz_[4];                                   \
            _Pragma("unroll")                                               \
            for (int i = 0; i < 4; ++i) {                                   \
                float4 mt = *(const float4*)&ldsMeta[wv][4 * g + i][0];     \
                Yx_[i] = mt.x; Yy_[i] = mt.y; Yz_[i] = mt.z;                \
                M0[i]  = __uint_as_float(MV[i].x << 16);                    \
                M1X[i] = __uint_as_float(MV[i].x & 0xffff0000u);            \
                M1Y[i] = __uint_as_float(MV[i].y << 16);                    \
                M1Z[i] = __uint_as_float(MV[i].y & 0xffff0000u);            \
            }                                                               \
            _Pragma("unroll")                                               \
            for (int p = 0; p < 5; ++p) {                                   \
                const int t = 4 * p + (Q);                                  \
                f32x4 w = {0.f, 0.f, 0.f, 0.f};                             \
                short8 b0 = *(const short8*)(ldsW3 + (size_t)(t * 2) * 512 + lane * 8);     \
                short8 b1 = *(const short8*)(ldsW3 + (size_t)(t * 2 + 1) * 512 + lane * 8); \
                w = __builtin_amdgcn_mfma_f32_16x16x32_bf16(h2f0, b0, w, 0, 0, 0);          \
                w = __builtin_amdgcn_mfma_f32_16x16x32_bf16(h2f1, b1, w, 0, 0, 0);          \
                _Pragma("unroll")                                           \
                for (int i = 0; i < 4; ++i) {                               \
                    float wv_ = w[i];                                       \
                    if (p == 0) {                                           \
                        a0q[Q] += wv_ * M0[i];                              \
                    } else if (p == 1) {                                    \
                        float tt = wv_ * M0[i];                             \
                        a1xq[Q] += tt * Yx_[i];                             \
                        a1yq[Q] += tt * Yy_[i];                             \
                        a1zq[Q] += tt * Yz_[i];                             \
                    } else if (p == 2) {                                    \
                        a1xq[Q] += wv_ * M1X[i];                            \
                        a1yq[Q] += wv_ * M1Y[i];                            \
                        a1zq[Q] += wv_ * M1Z[i];                            \
                    } else if (p == 3) {                                    \
                        a0q[Q] += wv_ * (M1X[i] * Yx_[i] + M1Y[i] * Yy_[i] + M1Z[i] * Yz_[i]); \
                    } else {                                                \
                        a1xq[Q] += wv_ * (M1Y[i] * Yz_[i] - M1Z[i] * Yy_[i]); \
                        a1yq[Q] += wv_ * (M1Z[i] * Yx_[i] - M1X[i] * Yz_[i]); \
                        a1zq[Q] += wv_ * (M1X[i] * Yy_[i] - M1Y[i] * Yx_[i]); \
                    }                                                       \
                }                                                           \
            }                                                               \
        }

            uint2 mA[4], mB[4];
            PFETCH(0, mA);
            PFETCH(1, mB);
            __builtin_amdgcn_sched_barrier(0);   // keep gathers issued here

            // ---- layer 1: 4 MFMAs; silu -> ldsH (swizzled bf16) ----
            #pragma unroll
            for (int t = 0; t < 4; ++t) {
                f32x4 h = {0.f, 0.f, 0.f, 0.f};
                short8 bf = *(const short8*)(W1B + (size_t)t * 512 + lane * 8);
                h = __builtin_amdgcn_mfma_f32_16x16x32_bf16(basisA, bf, h, 0, 0, 0);
                #pragma unroll
                for (int i = 0; i < 4; ++i) {
                    float x = h[i];
                    float h1 = x / (1.f + __expf(-x));
                    int row = 4 * g + i;
                    ldsH[wv][row * 64 + ((16 * t + c) ^ ((row & 7) << 3))] = bf16s(h1);
                }
            }
            short8 h1f0 = *(const short8*)&ldsH[wv][c * 64 + ((g * 8) ^ ((c & 7) << 3))];
            short8 h1f1 = *(const short8*)&ldsH[wv][c * 64 + ((32 + g * 8) ^ ((c & 7) << 3))];

            // ---- layer 2: 8 MFMAs; silu -> ldsH (reuse) ----
            #pragma unroll
            for (int t = 0; t < 4; ++t) {
                f32x4 h = {0.f, 0.f, 0.f, 0.f};
                short8 b0 = *(const short8*)(Wm2B + (size_t)(t * 2) * 512 + lane * 8);
                short8 b1 = *(const short8*)(Wm2B + (size_t)(t * 2 + 1) * 512 + lane * 8);
                h = __builtin_amdgcn_mfma_f32_16x16x32_bf16(h1f0, b0, h, 0, 0, 0);
                h = __builtin_amdgcn_mfma_f32_16x16x32_bf16(h1f1, b1, h, 0, 0, 0);
                #pragma unroll
                for (int i = 0; i < 4; ++i) {
                    float x = h[i];
                    float h2 = x / (1.f + __expf(-x));
                    int row = 4 * g + i;
                    ldsH[wv][row * 64 + ((16 * t + c) ^ ((row & 7) << 3))] = bf16s(h2);
                }
            }
            short8 h2f0 = *(const short8*)&ldsH[wv][c * 64 + ((g * 8) ^ ((c & 7) << 3))];
            short8 h2f1 = *(const short8*)&ldsH[wv][c * 64 + ((32 + g * 8) ^ ((c & 7) << 3))];

            // ---- layer 3 + fused messages, ping-pong pipelined over q ----
            COMPQ(0, mA);
            __builtin_amdgcn_sched_barrier(0);
            PFETCH(2, mA);
            COMPQ(1, mB);
            __builtin_amdgcn_sched_barrier(0);
            PFETCH(3, mB);
            COMPQ(2, mA);
            __builtin_amdgcn_sched_barrier(0);
            COMPQ(3, mB);
#undef PFETCH
#undef COMPQ
        }

        #pragma unroll
        for (int q = 0; q < 4; ++q) {
            a0q[q]  += __shfl_xor(a0q[q], 16);  a0q[q]  += __shfl_xor(a0q[q], 32);
            a1xq[q] += __shfl_xor(a1xq[q], 16); a1xq[q] += __shfl_xor(a1xq[q], 32);
            a1yq[q] += __shfl_xor(a1yq[q], 16); a1yq[q] += __shfl_xor(a1yq[q], 32);
            a1zq[q] += __shfl_xor(a1zq[q], 16); a1zq[q] += __shfl_xor(a1zq[q], 32);
        }
        if (lane < 16) {
            float* ar = acc + (size_t)n * 256;
            #pragma unroll
            for (int q = 0; q < 4; ++q) {
                ar[16 * q + lane]       = a0q[q];
                ar[64 + 16 * q + lane]  = a1xq[q];
                ar[128 + 16 * q + lane] = a1yq[q];
                ar[192 + 16 * q + lane] = a1zq[q];
            }
        }
    }
}

// ---------------------------------------------------------------------------
// Node epilogue v2: MFMA masked-species dense GEMM. (R13, unchanged)
// ---------------------------------------------------------------------------
__global__ __launch_bounds__(256) void node_out_kernel(
    const float* __restrict__ acc, const short* __restrict__ xpk,
    const int* __restrict__ node_specie, const short* __restrict__ WoB,
    float* __restrict__ out, int N)
{
    __shared__ float ldsOut[4][16][256];   // 64KB
    const int lane = threadIdx.x & 63;
    const int wv   = threadIdx.x >> 6;
    const int c = lane & 15, g = lane >> 4;
    const int n0 = (blockIdx.x * 4 + wv) * 16;
    if (n0 >= N) return;

    const int nc = min(n0 + c, N - 1);        // this lane's A-row node
    const int sp_c = node_specie[nc];
    const short8 z8 = {0, 0, 0, 0, 0, 0, 0, 0};

    short8 x0f[2], a0hi[2], a0lo[2];
    #pragma unroll
    for (int kh = 0; kh < 2; ++kh) {
        x0f[kh] = *(const short8*)&xpk[(size_t)nc * 256 + kh * 32 + g * 8];
        const float* ap = acc + (size_t)nc * 256 + kh * 32 + g * 8;
        #pragma unroll
        for (int i = 0; i < 8; ++i) {
            float v = 0.25f * ap[i];
            unsigned h = bf16u(v);
            a0hi[kh][i] = (short)h;
            a0lo[kh][i] = (short)bf16u(v - __uint_as_float(h << 16));
        }
    }

    f32x4 w0[8];
    #pragma unroll
    for (int t = 0; t < 8; ++t) w0[t] = (f32x4){0.f, 0.f, 0.f, 0.f};
    #pragma unroll
    for (int t = 0; t < 8; ++t)
        #pragma unroll
        for (int kh = 0; kh < 2; ++kh) {
            short8 b = *(const short8*)(WoB + (size_t)(t * 2 + kh) * 512 + lane * 8);
            w0[t] = __builtin_amdgcn_mfma_f32_16x16x32_bf16(a0hi[kh], b, w0[t], 0, 0, 0);
            w0[t] = __builtin_amdgcn_mfma_f32_16x16x32_bf16(a0lo[kh], b, w0[t], 0, 0, 0);
        }
    #pragma unroll
    for (int s = 0; s < 5; ++s) {
        if (!__any(sp_c == s)) continue;
        short8 mk0 = (sp_c == s) ? x0f[0] : z8;
        short8 mk1 = (sp_c == s) ? x0f[1] : z8;
        #pragma unroll
        for (int t = 0; t < 8; ++t) {
            short8 b0 = *(const short8*)(WoB + (size_t)(16 + s * 16 + t * 2) * 512 + lane * 8);
            short8 b1 = *(const short8*)(WoB + (size_t)(16 + s * 16 + t * 2 + 1) * 512 + lane * 8);
            w0[t] = __builtin_amdgcn_mfma_f32_16x16x32_bf16(mk0, b0, w0[t], 0, 0, 0);
            w0[t] = __builtin_amdgcn_mfma_f32_16x16x32_bf16(mk1, b1, w0[t], 0, 0, 0);
        }
    }
    float gate[4][4];
    #pragma unroll
    for (int t = 0; t < 8; ++t)
        #pragma unroll
        for (int i = 0; i < 4; ++i) {
            float x = w0[t][i];
            float sv = x / (1.f + __expf(-x));
            if (t < 4) ldsOut[wv][4 * g + i][16 * t + c] = sv;
            else       gate[t - 4][i] = sv;
        }

    short8 x1f[3][2], a1hi[3][2], a1lo[3][2];
    #pragma unroll
    for (int j = 0; j < 3; ++j)
        #pragma unroll
        for (int kh = 0; kh < 2; ++kh) {
            x1f[j][kh] = *(const short8*)&xpk[(size_t)nc * 256 + (1 + j) * 64 + kh * 32 + g * 8];
            const float* ap = acc + (size_t)nc * 256 + 64 + 64 * j + kh * 32 + g * 8;
            #pragma unroll
            for (int i = 0; i < 8; ++i) {
                float v = 0.25f * ap[i];
                unsigned h = bf16u(v);
                a1hi[j][kh][i] = (short)h;
                a1lo[j][kh][i] = (short)bf16u(v - __uint_as_float(h << 16));
            }
        }

    f32x4 w1[3][4];
    #pragma unroll
    for (int j = 0; j < 3; ++j)
        #pragma unroll
        for (int t = 0; t < 4; ++t) w1[j][t] = (f32x4){0.f, 0.f, 0.f, 0.f};
    #pragma unroll
    for (int t = 0; t < 4; ++t)
        #pragma unroll
        for (int kh = 0; kh < 2; ++kh) {
            short8 b = *(const short8*)(WoB + (size_t)(96 + t * 2 + kh) * 512 + lane * 8);
            #pragma unroll
            for (int j = 0; j < 3; ++j) {
                w1[j][t] = __builtin_amdgcn_mfma_f32_16x16x32_bf16(a1hi[j][kh], b, w1[j][t], 0, 0, 0);
                w1[j][t] = __builtin_amdgcn_mfma_f32_16x16x32_bf16(a1lo[j][kh], b, w1[j][t], 0, 0, 0);
            }
        }
    #pragma unroll
    for (int s = 0; s < 5; ++s) {
        if (!__any(sp_c == s)) continue;
        short8 m1[3][2];
        #pragma unroll
        for (int j = 0; j < 3; ++j) {
            m1[j][0] = (sp_c == s) ? x1f[j][0] : z8;
            m1[j][1] = (sp_c == s) ? x1f[j][1] : z8;
        }
        #pragma unroll
        for (int t = 0; t < 4; ++t)
            #pragma unroll
            for (int kh = 0; kh < 2; ++kh) {
                short8 b = *(const short8*)(WoB + (size_t)(104 + s * 8 + t * 2 + kh) * 512 + lane * 8);
                #pragma unroll
                for (int j = 0; j < 3; ++j)
                    w1[j][t] = __builtin_amdgcn_mfma_f32_16x16x32_bf16(m1[j][kh], b, w1[j][t], 0, 0, 0);
            }
    }
    #pragma unroll
    for (int j = 0; j < 3; ++j)
        #pragma unroll
        for (int t = 0; t < 4; ++t)
            #pragma unroll
            for (int i = 0; i < 4; ++i)
                ldsOut[wv][4 * g + i][64 + (16 * t + c) * 3 + j] = w1[j][t][i] * gate[t][i];

    #pragma unroll 4
    for (int r = 0; r < 16; ++r) {
        int nn = n0 + r;
        if (nn < N)
            *(float4*)&out[(size_t)nn * 256 + lane * 4] =
                *(const float4*)&ldsOut[wv][r][lane * 4];
    }
}

// ---------------------------------------------------------------------------
extern "C" void kernel_launch(void* const* d_in, const int* in_sizes, int n_in,
                              void* d_out, int out_size, void* d_ws, size_t ws_size,
                              hipStream_t stream) {
    const float* vectors     = (const float*)d_in[0];
    const float* node_feats  = (const float*)d_in[1];
    const int*   node_specie = (const int*)d_in[2];
    const int*   senders     = (const int*)d_in[3];
    const int*   receivers   = (const int*)d_in[4];
    const float* W0_up       = (const float*)d_in[5];
    const float* W1_up       = (const float*)d_in[6];
    const float* Wm1         = (const float*)d_in[7];
    const float* Wm2         = (const float*)d_in[8];
    const float* Wm3         = (const float*)d_in[9];
    const float* Ws0         = (const float*)d_in[10];
    const float* Ws1         = (const float*)d_in[11];
    const float* Wd0         = (const float*)d_in[12];
    const float* Wd1         = (const float*)d_in[13];
    float* out = (float*)d_out;

    int E = in_sizes[0] / 3;
    int N = in_sizes[1] / 256;
    int nblk = (N + 1023) / 1024;

    char* wp = (char*)d_ws;
    uint2* ubf    = (uint2*)wp;                 wp += (size_t)N * 64 * 8;
    float* acc    = (float*)wp;                 wp += (size_t)N * 256 * 4;
    short* xpk    = (short*)wp;                 wp += (size_t)N * 256 * 2;
    uint4* epackA = (uint4*)wp;                 wp += (size_t)(E + 16) * 16;
    float4* epackB = (float4*)wp;               wp += (size_t)(E + 16) * 16;
    short* W1B    = (short*)wp;                 wp += 4 * 512 * 2;
    short* Wm2B   = (short*)wp;                 wp += 8 * 512 * 2;
    short* W3B    = (short*)wp;                 wp += 40 * 512 * 2;
    short* WoB    = (short*)wp;                 wp += 144 * 512 * 2;
    int*   cnt    = (int*)wp;                   wp += (size_t)N * 4;
    int*   offs   = (int*)wp;                   wp += (size_t)(N + 1) * 4;
    int*   cursor = (int*)wp;                   wp += (size_t)N * 4;
    int*   part   = (int*)wp;                   wp += (size_t)(nblk + 1) * 4;

    prep_kernel<<<80, 256, 0, stream>>>(
        Wm1, Wm2, Wm3, Wd0, Ws0, Wd1, Ws1, W1B, Wm2B, W3B, WoB, cnt, N);
    hist_kernel<<<1024, 256, 0, stream>>>(receivers, cnt, E);
    scan1_kernel<<<nblk, 256, 0, stream>>>(cnt, offs, part, N);
    scan2_kernel<<<1, 64, 0, stream>>>(part, offs, nblk, N);
    scan3_kernel<<<nblk, 256, 0, stream>>>(offs, cursor, part, N);
    fill_pack_kernel<<<1024, 256, 0, stream>>>(
        vectors, senders, receivers, cursor, epackA, epackB, E);
    node_up_kernel<<<(N + 3) / 4, 256, 0, stream>>>(
        node_feats, W0_up, W1_up, ubf, xpk, N);
    const int EDGE_BLOCKS = 768;
    edge_kernel<<<EDGE_BLOCKS, 256, 0, stream>>>(
        epackA, epackB, offs, ubf, W1B, Wm2B, W3B, acc, N, EDGE_BLOCKS * 4);
    int ngroups = (N + 15) / 16;
    node_out_kernel<<<(ngroups + 3) / 4, 256, 0, stream>>>(
        acc, xpk, node_specie, WoB, out, N);
}

// Round 16
// 253.861 us; speedup vs baseline: 2.1283x; 1.1165x over previous
//
#include <hip/hip_runtime.h>
#include <hip/hip_bf16.h>

typedef __attribute__((ext_vector_type(8))) short short8;
typedef __attribute__((ext_vector_type(4))) float f32x4;

__device__ __forceinline__ unsigned bf16u(float x) {
    unsigned u = __float_as_uint(x);
    return (u + 0x7fffu + ((u >> 16) & 1u)) >> 16;
}
__device__ __forceinline__ short bf16s(float x) { return (short)bf16u(x); }

// ---------------------------------------------------------------------------
// Prep (merged): zero cnt + pack ALL weights into MFMA B-fragments.
// ---------------------------------------------------------------------------
__global__ __launch_bounds__(256) void prep_kernel(
    const float* __restrict__ Wm1, const float* __restrict__ Wm2,
    const float* __restrict__ Wm3,
    const float* __restrict__ Wd0, const float* __restrict__ Ws0,
    const float* __restrict__ Wd1, const float* __restrict__ Ws1,
    short* __restrict__ W1B, short* __restrict__ Wm2B, short* __restrict__ W3B,
    short* __restrict__ WoB, int* __restrict__ cnt, int N)
{
    const int tid = blockIdx.x * 256 + threadIdx.x;
    const int nth = gridDim.x * 256;

    for (int i = tid; i < N; i += nth) cnt[i] = 0;

    for (int idx = tid; idx < 52 * 64; idx += nth) {
        int l = idx & 63, f = idx >> 6;
        int g = l >> 4, c = l & 15;
        short8 v;
        if (f < 4) {
            #pragma unroll
            for (int i = 0; i < 8; ++i)
                v[i] = (g == 0) ? bf16s(Wm1[(size_t)i * 64 + f * 16 + c]) : (short)0;
            *(short8*)(W1B + (size_t)f * 512 + l * 8) = v;
        } else if (f < 12) {
            int f2 = f - 4, t = f2 >> 1, kh = f2 & 1;
            #pragma unroll
            for (int i = 0; i < 8; ++i)
                v[i] = bf16s(Wm2[(size_t)(kh * 32 + g * 8 + i) * 64 + t * 16 + c]);
            *(short8*)(Wm2B + (size_t)f2 * 512 + l * 8) = v;
        } else {
            int f3 = f - 12, t = f3 >> 1, kh = f3 & 1;
            #pragma unroll
            for (int i = 0; i < 8; ++i)
                v[i] = bf16s(Wm3[(size_t)(kh * 32 + g * 8 + i) * 320 + t * 16 + c]);
            *(short8*)(W3B + (size_t)f3 * 512 + l * 8) = v;
        }
    }

    for (int idx = tid; idx < 144 * 64; idx += nth) {
        int l = idx & 63, f = idx >> 6;
        int g = l >> 4, c = l & 15;
        short8 v;
        if (f < 16) {
            int t = f >> 1, kh = f & 1;
            #pragma unroll
            for (int i = 0; i < 8; ++i)
                v[i] = bf16s(Wd0[(size_t)(kh * 32 + g * 8 + i) * 128 + t * 16 + c]);
        } else if (f < 96) {
            int s = (f - 16) >> 4, r = (f - 16) & 15, t = r >> 1, kh = r & 1;
            #pragma unroll
            for (int i = 0; i < 8; ++i)
                v[i] = bf16s(Ws0[((size_t)s * 64 + kh * 32 + g * 8 + i) * 128 + t * 16 + c]);
        } else if (f < 104) {
            int r = f - 96, t = r >> 1, kh = r & 1;
            #pragma unroll
            for (int i = 0; i < 8; ++i)
                v[i] = bf16s(Wd1[(size_t)(kh * 32 + g * 8 + i) * 64 + t * 16 + c]);
        } else {
            int s = (f - 104) >> 3, r = (f - 104) & 7, t = r >> 1, kh = r & 1;
            #pragma unroll
            for (int i = 0; i < 8; ++i)
                v[i] = bf16s(Ws1[((size_t)s * 64 + kh * 32 + g * 8 + i) * 64 + t * 16 + c]);
        }
        *(short8*)(WoB + (size_t)f * 512 + l * 8) = v;
    }
}

// ---------------------------------------------------------------------------
// CSR build
// ---------------------------------------------------------------------------
__global__ __launch_bounds__(256) void hist_kernel(
    const int* __restrict__ receivers, int* __restrict__ cnt, int E)
{
    int i = blockIdx.x * 256 + threadIdx.x;
    int stride = gridDim.x * 256;
    for (; i < E; i += stride) atomicAdd(&cnt[receivers[i]], 1);
}

__global__ __launch_bounds__(256) void scan1_kernel(
    const int* __restrict__ cnt, int* __restrict__ offs,
    int* __restrict__ part, int N)
{
    __shared__ int a_[256], b_[256];
    const int b = blockIdx.x, t = threadIdx.x;
    const int base = b * 1024 + t * 4;
    int v[4];
    #pragma unroll
    for (int k = 0; k < 4; ++k) v[k] = (base + k < N) ? cnt[base + k] : 0;
    int sum = v[0] + v[1] + v[2] + v[3];
    a_[t] = sum;
    __syncthreads();
    int* src = a_; int* dst = b_;
    for (int off = 1; off < 256; off <<= 1) {
        dst[t] = src[t] + ((t >= off) ? src[t - off] : 0);
        __syncthreads();
        int* tmp = src; src = dst; dst = tmp;
    }
    int excl = src[t] - sum;
    if (t == 0) part[b] = src[255];
    int run = excl;
    #pragma unroll
    for (int k = 0; k < 4; ++k) {
        if (base + k < N) offs[base + k] = run;
        run += v[k];
    }
}

// scan2+scan3 merged: each block redundantly scans the (small) partials array,
// adds its base, mirrors into cursor. Block 0 writes offs[N].
__global__ __launch_bounds__(256) void scan23_kernel(
    int* __restrict__ offs, int* __restrict__ cursor,
    const int* __restrict__ part, int nblk, int N)
{
    __shared__ int base_s, total_s;
    const int b = blockIdx.x, t = threadIdx.x;
    if (t == 0) {
        int s = 0, tot = 0;
        for (int i = 0; i < nblk; ++i) {
            if (i < b) s += part[i];
            tot += part[i];
        }
        base_s = s; total_s = tot;
    }
    __syncthreads();
    const int add = base_s;
    const int base = b * 1024 + t * 4;
    #pragma unroll
    for (int k = 0; k < 4; ++k) {
        int i = base + k;
        if (i < N) {
            int o = offs[i] + add;
            offs[i] = o;
            cursor[i] = o;
        }
    }
    if (b == 0 && t == 0) offs[N] = total_s;
}

// ---------------------------------------------------------------------------
// Merged fill_pack + node_up (independent work, one dispatch).
//  blocks [0,FPB): scatter per-edge packed records into CSR slots
//  blocks [FPB,..): node up-projection -> ubf (bf16x4) + xpk (bf16 feats)
// ---------------------------------------------------------------------------
__global__ __launch_bounds__(256) void fpnu_kernel(
    const float* __restrict__ vectors, const int* __restrict__ senders,
    const int* __restrict__ receivers, int* __restrict__ cursor,
    uint4* __restrict__ epackA, float4* __restrict__ epackB,
    const float* __restrict__ node_feats, const float* __restrict__ W0_up,
    const float* __restrict__ W1_up, uint2* __restrict__ ubf,
    short* __restrict__ xpk, int E, int N, int FPB)
{
    if (blockIdx.x < FPB) {
        int i = blockIdx.x * 256 + threadIdx.x;
        int stride = FPB * 256;
        for (; i < E; i += stride) {
            int pos = atomicAdd(&cursor[receivers[i]], 1);
            float vx = vectors[3 * (size_t)i + 0];
            float vy = vectors[3 * (size_t)i + 1];
            float vz = vectors[3 * (size_t)i + 2];
            float r = sqrtf(vx * vx + vy * vy + vz * vz);
            float ir = (r != 0.f) ? 1.f / r : 0.f;
            float ang = r * 0.6283185307179586f;   // pi/5
            float s1, c1;
            __sincosf(ang, &s1, &c1);
            float tc = 2.f * c1;
            float sb = s1, sp = 0.f;
            float coef = 0.6324555320336759f * ir;
            unsigned bw[4];
            #pragma unroll
            for (int h = 0; h < 4; ++h) {
                unsigned lo = bf16u(sb * coef);
                float nx = tc * sb - sp; sp = sb; sb = nx;
                unsigned hi = bf16u(sb * coef);
                nx = tc * sb - sp; sp = sb; sb = nx;
                bw[h] = lo | (hi << 16);
            }
            epackA[pos] = make_uint4(bw[0], bw[1], bw[2], bw[3]);
            epackB[pos] = make_float4(vx * ir, vy * ir, vz * ir,
                                      __int_as_float(senders[i]));
        }
    } else {
        int nb = (blockIdx.x - FPB) * 4 + (threadIdx.x >> 6);
        int d  = threadIdx.x & 63;
        if (nb >= N) return;
        const float* nf = node_feats + (size_t)nb * 256;
        float a0 = 0.f, ax = 0.f, ay = 0.f, az = 0.f;
        #pragma unroll 4
        for (int cc = 0; cc < 64; ++cc) {
            float w0 = W0_up[cc * 64 + d];
            float w1 = W1_up[cc * 64 + d];
            a0 += nf[cc] * w0;
            ax += nf[64 + cc * 3 + 0] * w1;
            ay += nf[64 + cc * 3 + 1] * w1;
            az += nf[64 + cc * 3 + 2] * w1;
        }
        ubf[(size_t)nb * 64 + d] = make_uint2(bf16u(a0) | (bf16u(ax) << 16),
                                              bf16u(ay) | (bf16u(az) << 16));
        short* xp = xpk + (size_t)nb * 256;
        xp[d]       = bf16s(nf[d]);
        xp[64 + d]  = bf16s(nf[64 + d * 3 + 0]);
        xp[128 + d] = bf16s(nf[64 + d * 3 + 1]);
        xp[192 + d] = bf16s(nf[64 + d * 3 + 2]);
    }
}

// ---------------------------------------------------------------------------
// SPLIT PATH kernel A: dense MLP over flat 16-row CSR windows -> wmix bf16.
// No node semantics, no message state: pure MFMA pipeline at low VGPR.
// Persistent (W3B staged once per block).
// ---------------------------------------------------------------------------
__global__ __launch_bounds__(256) void mlp_kernel(
    const uint4* __restrict__ epackA,
    const short* __restrict__ W1B, const short* __restrict__ Wm2B,
    const short* __restrict__ W3B, unsigned short* __restrict__ wmix,
    int P, int nwaves)
{
    __shared__ __align__(16) short ldsW3[40 * 512];
    __shared__ __align__(16) short ldsH[4][1024];

    {
        const short8* src = (const short8*)W3B;
        short8* dst = (short8*)ldsW3;
        for (int i = threadIdx.x; i < 2560; i += 256) dst[i] = src[i];
    }
    __syncthreads();

    const int lane = threadIdx.x & 63;
    const int wv   = threadIdx.x >> 6;
    const int gw   = blockIdx.x * 4 + wv;
    const int c = lane & 15, g = lane >> 4;
    const int nwin = (P + 15) >> 4;

    for (int w = gw; w < nwin; w += nwaves) {
        const int p0 = w << 4;

        short8 basisA = {0, 0, 0, 0, 0, 0, 0, 0};
        if (lane < 16) {
            uint4 ba = epackA[p0 + lane];   // tail rows garbage but never stored
            union { uint4 u4v; short8 s8; } cv;
            cv.u4v = ba;
            basisA = cv.s8;
        }

        // layer 1: 4 MFMAs -> silu -> ldsH
        #pragma unroll
        for (int t = 0; t < 4; ++t) {
            f32x4 h = {0.f, 0.f, 0.f, 0.f};
            short8 bf = *(const short8*)(W1B + (size_t)t * 512 + lane * 8);
            h = __builtin_amdgcn_mfma_f32_16x16x32_bf16(basisA, bf, h, 0, 0, 0);
            #pragma unroll
            for (int i = 0; i < 4; ++i) {
                float x = h[i];
                float h1 = x / (1.f + __expf(-x));
                int row = 4 * g + i;
                ldsH[wv][row * 64 + ((16 * t + c) ^ ((row & 7) << 3))] = bf16s(h1);
            }
        }
        short8 h1f0 = *(const short8*)&ldsH[wv][c * 64 + ((g * 8) ^ ((c & 7) << 3))];
        short8 h1f1 = *(const short8*)&ldsH[wv][c * 64 + ((32 + g * 8) ^ ((c & 7) << 3))];

        // layer 2: 8 MFMAs -> silu -> ldsH
        #pragma unroll
        for (int t = 0; t < 4; ++t) {
            f32x4 h = {0.f, 0.f, 0.f, 0.f};
            short8 b0 = *(const short8*)(Wm2B + (size_t)(t * 2) * 512 + lane * 8);
            short8 b1 = *(const short8*)(Wm2B + (size_t)(t * 2 + 1) * 512 + lane * 8);
            h = __builtin_amdgcn_mfma_f32_16x16x32_bf16(h1f0, b0, h, 0, 0, 0);
            h = __builtin_amdgcn_mfma_f32_16x16x32_bf16(h1f1, b1, h, 0, 0, 0);
            #pragma unroll
            for (int i = 0; i < 4; ++i) {
                float x = h[i];
                float h2 = x / (1.f + __expf(-x));
                int row = 4 * g + i;
                ldsH[wv][row * 64 + ((16 * t + c) ^ ((row & 7) << 3))] = bf16s(h2);
            }
        }
        short8 h2f0 = *(const short8*)&ldsH[wv][c * 64 + ((g * 8) ^ ((c & 7) << 3))];
        short8 h2f1 = *(const short8*)&ldsH[wv][c * 64 + ((32 + g * 8) ^ ((c & 7) << 3))];

        // layer 3: 40 MFMAs -> store wmix rows [pos][320]
        size_t rowOfs[4];
        bool ok[4];
        #pragma unroll
        for (int i = 0; i < 4; ++i) {
            int row = p0 + 4 * g + i;
            ok[i] = (row < P);
            rowOfs[i] = (size_t)row * 320;
        }
        #pragma unroll
        for (int t = 0; t < 20; ++t) {
            f32x4 wq = {0.f, 0.f, 0.f, 0.f};
            short8 b0 = *(const short8*)(ldsW3 + (size_t)(t * 2) * 512 + lane * 8);
            short8 b1 = *(const short8*)(ldsW3 + (size_t)(t * 2 + 1) * 512 + lane * 8);
            wq = __builtin_amdgcn_mfma_f32_16x16x32_bf16(h2f0, b0, wq, 0, 0, 0);
            wq = __builtin_amdgcn_mfma_f32_16x16x32_bf16(h2f1, b1, wq, 0, 0, 0);
            const int col = (t >> 2) * 64 + (t & 3) * 16 + c;
            #pragma unroll
            for (int i = 0; i < 4; ++i)
                if (ok[i]) wmix[rowOfs[i] + col] = (unsigned short)bf16u(wq[i]);
        }
    }
}

// ---------------------------------------------------------------------------
// SPLIT PATH kernel B: gather + messages + accumulate. Wave per node, lane=d.
// No MFMA, tiny LDS/VGPR -> high occupancy hides gather latency.
// ---------------------------------------------------------------------------
__global__ __launch_bounds__(256) void gather_kernel(
    const float4* __restrict__ epackB, const int* __restrict__ offs,
    const uint2* __restrict__ ubf, const unsigned short* __restrict__ wmix,
    float* __restrict__ acc, int N)
{
    const int lane = threadIdx.x & 63;
    const int n = blockIdx.x * 4 + (threadIdx.x >> 6);
    if (n >= N) return;

    const int beg = offs[n], end = offs[n + 1];
    float a0 = 0.f, a1x = 0.f, a1y = 0.f, a1z = 0.f;

    #pragma unroll 2
    for (int pos = beg; pos < end; ++pos) {
        float4 mb = epackB[pos];                 // uniform: Y.xyz + sender
        int snd = __float_as_int(mb.w);
        uint2 mu = ubf[(size_t)snd * 64 + lane]; // coalesced 512B row
        const unsigned short* wr = wmix + (size_t)pos * 320;
        float w00  = __uint_as_float((unsigned)wr[lane]        << 16);
        float w01  = __uint_as_float((unsigned)wr[64 + lane]   << 16);
        float w10  = __uint_as_float((unsigned)wr[128 + lane]  << 16);
        float w11d = __uint_as_float((unsigned)wr[192 + lane]  << 16);
        float w11c = __uint_as_float((unsigned)wr[256 + lane]  << 16);
        float m0  = __uint_as_float(mu.x << 16);
        float m1x = __uint_as_float(mu.x & 0xffff0000u);
        float m1y = __uint_as_float(mu.y << 16);
        float m1z = __uint_as_float(mu.y & 0xffff0000u);

        float dotv = m1x * mb.x + m1y * mb.y + m1z * mb.z;
        a0 += w00 * m0 + w11d * dotv;
        float wm = w01 * m0;
        a1x += wm * mb.x + w10 * m1x + w11c * (m1y * mb.z - m1z * mb.y);
        a1y += wm * mb.y + w10 * m1y + w11c * (m1z * mb.x - m1x * mb.z);
        a1z += wm * mb.z + w10 * m1z + w11c * (m1x * mb.y - m1y * mb.x);
    }

    float* ar = acc + (size_t)n * 256;
    ar[lane]       = a0;
    ar[64 + lane]  = a1x;
    ar[128 + lane] = a1y;
    ar[192 + lane] = a1z;
}

// ---------------------------------------------------------------------------
// FALLBACK: fused edge kernel (R13 version, used when ws too small for wmix)
// ---------------------------------------------------------------------------
__global__ __launch_bounds__(256) void edge_kernel(
    const uint4* __restrict__ epackA, const float4* __restrict__ epackB,
    const int* __restrict__ offs, const uint2* __restrict__ ubf,
    const short* __restrict__ W1B, const short* __restrict__ Wm2B,
    const short* __restrict__ W3B, float* __restrict__ acc,
    int N, int nwaves)
{
    __shared__ __align__(16) short ldsW3[40 * 512];
    __shared__ __align__(16) short ldsH[4][1024];
    __shared__ __align__(16) float ldsMeta[4][16][4];

    {
        const short8* src = (const short8*)W3B;
        short8* dst = (short8*)ldsW3;
        for (int i = threadIdx.x; i < 2560; i += 256) dst[i] = src[i];
    }
    __syncthreads();

    const int lane = threadIdx.x & 63;
    const int wv   = threadIdx.x >> 6;
    const int gw   = blockIdx.x * 4 + wv;
    const int c = lane & 15, g = lane >> 4;

    for (int n = gw; n < N; n += nwaves) {
        float a0q[4]  = {0.f, 0.f, 0.f, 0.f};
        float a1xq[4] = {0.f, 0.f, 0.f, 0.f};
        float a1yq[4] = {0.f, 0.f, 0.f, 0.f};
        float a1zq[4] = {0.f, 0.f, 0.f, 0.f};
        const int beg = offs[n], end = offs[n + 1];

        for (int p0 = beg; p0 < end; p0 += 16) {
            const int m = end - p0;
            short8 basisA = {0, 0, 0, 0, 0, 0, 0, 0};
            if (lane < 16) {
                uint4 ba = epackA[p0 + lane];
                float4 mb = epackB[p0 + lane];
                if (lane >= m) {
                    ba = make_uint4(0u, 0u, 0u, 0u);
                    mb = make_float4(0.f, 0.f, 0.f, __int_as_float(0));
                }
                union { uint4 u4v; short8 s8; } cv;
                cv.u4v = ba;
                basisA = cv.s8;
                *(float4*)&ldsMeta[wv][lane][0] = mb;
            }
            float Yx[4], Yy[4], Yz[4];
            int snd[4];
            #pragma unroll
            for (int i = 0; i < 4; ++i) {
                float4 mt = *(const float4*)&ldsMeta[wv][4 * g + i][0];
                Yx[i] = mt.x; Yy[i] = mt.y; Yz[i] = mt.z;
                snd[i] = __float_as_int(mt.w);
            }

#define PFETCH(Q, MV)                                                       \
            _Pragma("unroll")                                               \
            for (int i = 0; i < 4; ++i)                                     \
                MV[i] = ubf[(size_t)snd[i] * 64 + 16 * (Q) + c];

#define COMPQ(Q, MV)                                                        \
        {                                                                   \
            float M0[4], M1X[4], M1Y[4], M1Z[4];                            \
            _Pragma("unroll")                                               \
            for (int i = 0; i < 4; ++i) {                                   \
                M0[i]  = __uint_as_float(MV[i].x << 16);                    \
                M1X[i] = __uint_as_float(MV[i].x & 0xffff0000u);            \
                M1Y[i] = __uint_as_float(MV[i].y << 16);                    \
                M1Z[i] = __uint_as_float(MV[i].y & 0xffff0000u);            \
            }                                                               \
            _Pragma("unroll")                                               \
            for (int p = 0; p < 5; ++p) {                                   \
                const int t = 4 * p + (Q);                                  \
                f32x4 w = {0.f, 0.f, 0.f, 0.f};                             \
                short8 b0 = *(const short8*)(ldsW3 + (size_t)(t * 2) * 512 + lane * 8);     \
                short8 b1 = *(const short8*)(ldsW3 + (size_t)(t * 2 + 1) * 512 + lane * 8); \
                w = __builtin_amdgcn_mfma_f32_16x16x32_bf16(h2f0, b0, w, 0, 0, 0);          \
                w = __builtin_amdgcn_mfma_f32_16x16x32_bf16(h2f1, b1, w, 0, 0, 0);          \
                _Pragma("unroll")                                           \
                for (int i = 0; i < 4; ++i) {                               \
                    float wv_ = w[i];                                       \
                    if (p == 0) {                                           \
                        a0q[Q] += wv_ * M0[i];                              \
                    } else if (p == 1) {                                    \
                        float tt = wv_ * M0[i];                             \
                        a1xq[Q] += tt * Yx[i];                              \
                        a1yq[Q] += tt * Yy[i];                              \
                        a1zq[Q] += tt * Yz[i];                              \
                    } else if (p == 2) {                                    \
                        a1xq[Q] += wv_ * M1X[i];                            \
                        a1yq[Q] += wv_ * M1Y[i];                            \
                        a1zq[Q] += wv_ * M1Z[i];                            \
                    } else if (p == 3) {                                    \
                        a0q[Q] += wv_ * (M1X[i] * Yx[i] + M1Y[i] * Yy[i] + M1Z[i] * Yz[i]); \
                    } else {                                                \
                        a1xq[Q] += wv_ * (M1Y[i] * Yz[i] - M1Z[i] * Yy[i]); \
                        a1yq[Q] += wv_ * (M1Z[i] * Yx[i] - M1X[i] * Yz[i]); \
                        a1zq[Q] += wv_ * (M1X[i] * Yy[i] - M1Y[i] * Yx[i]); \
                    }                                                       \
                }                                                           \
            }                                                               \
        }

            uint2 mA[4], mB[4];
            PFETCH(0, mA);
            PFETCH(1, mB);
            __builtin_amdgcn_sched_barrier(0);

            #pragma unroll
            for (int t = 0; t < 4; ++t) {
                f32x4 h = {0.f, 0.f, 0.f, 0.f};
                short8 bf = *(const short8*)(W1B + (size_t)t * 512 + lane * 8);
                h = __builtin_amdgcn_mfma_f32_16x16x32_bf16(basisA, bf, h, 0, 0, 0);
                #pragma unroll
                for (int i = 0; i < 4; ++i) {
                    float x = h[i];
                    float h1 = x / (1.f + __expf(-x));
                    int row = 4 * g + i;
                    ldsH[wv][row * 64 + ((16 * t + c) ^ ((row & 7) << 3))] = bf16s(h1);
                }
            }
            short8 h1f0 = *(const short8*)&ldsH[wv][c * 64 + ((g * 8) ^ ((c & 7) << 3))];
            short8 h1f1 = *(const short8*)&ldsH[wv][c * 64 + ((32 + g * 8) ^ ((c & 7) << 3))];

            #pragma unroll
            for (int t = 0; t < 4; ++t) {
                f32x4 h = {0.f, 0.f, 0.f, 0.f};
                short8 b0 = *(const short8*)(Wm2B + (size_t)(t * 2) * 512 + lane * 8);
                short8 b1 = *(const short8*)(Wm2B + (size_t)(t * 2 + 1) * 512 + lane * 8);
                h = __builtin_amdgcn_mfma_f32_16x16x32_bf16(h1f0, b0, h, 0, 0, 0);
                h = __builtin_amdgcn_mfma_f32_16x16x32_bf16(h1f1, b1, h, 0, 0, 0);
                #pragma unroll
                for (int i = 0; i < 4; ++i) {
                    float x = h[i];
                    float h2 = x / (1.f + __expf(-x));
                    int row = 4 * g + i;
                    ldsH[wv][row * 64 + ((16 * t + c) ^ ((row & 7) << 3))] = bf16s(h2);
                }
            }
            short8 h2f0 = *(const short8*)&ldsH[wv][c * 64 + ((g * 8) ^ ((c & 7) << 3))];
            short8 h2f1 = *(const short8*)&ldsH[wv][c * 64 + ((32 + g * 8) ^ ((c & 7) << 3))];

            COMPQ(0, mA);
            __builtin_amdgcn_sched_barrier(0);
            PFETCH(2, mA);
            COMPQ(1, mB);
            __builtin_amdgcn_sched_barrier(0);
            PFETCH(3, mB);
            COMPQ(2, mA);
            __builtin_amdgcn_sched_barrier(0);
            COMPQ(3, mB);
#undef PFETCH
#undef COMPQ
        }

        #pragma unroll
        for (int q = 0; q < 4; ++q) {
            a0q[q]  += __shfl_xor(a0q[q], 16);  a0q[q]  += __shfl_xor(a0q[q], 32);
            a1xq[q] += __shfl_xor(a1xq[q], 16); a1xq[q] += __shfl_xor(a1xq[q], 32);
            a1yq[q] += __shfl_xor(a1yq[q], 16); a1yq[q] += __shfl_xor(a1yq[q], 32);
            a1zq[q] += __shfl_xor(a1zq[q], 16); a1zq[q] += __shfl_xor(a1zq[q], 32);
        }
        if (lane < 16) {
            float* ar = acc + (size_t)n * 256;
            #pragma unroll
            for (int q = 0; q < 4; ++q) {
                ar[16 * q + lane]       = a0q[q];
                ar[64 + 16 * q + lane]  = a1xq[q];
                ar[128 + 16 * q + lane] = a1yq[q];
                ar[192 + 16 * q + lane] = a1zq[q];
            }
        }
    }
}

// ---------------------------------------------------------------------------
// Node epilogue: MFMA masked-species dense GEMM. (unchanged)
// ---------------------------------------------------------------------------
__global__ __launch_bounds__(256) void node_out_kernel(
    const float* __restrict__ acc, const short* __restrict__ xpk,
    const int* __restrict__ node_specie, const short* __restrict__ WoB,
    float* __restrict__ out, int N)
{
    __shared__ float ldsOut[4][16][256];
    const int lane = threadIdx.x & 63;
    const int wv   = threadIdx.x >> 6;
    const int c = lane & 15, g = lane >> 4;
    const int n0 = (blockIdx.x * 4 + wv) * 16;
    if (n0 >= N) return;

    const int nc = min(n0 + c, N - 1);
    const int sp_c = node_specie[nc];
    const short8 z8 = {0, 0, 0, 0, 0, 0, 0, 0};

    short8 x0f[2], a0hi[2], a0lo[2];
    #pragma unroll
    for (int kh = 0; kh < 2; ++kh) {
        x0f[kh] = *(const short8*)&xpk[(size_t)nc * 256 + kh * 32 + g * 8];
        const float* ap = acc + (size_t)nc * 256 + kh * 32 + g * 8;
        #pragma unroll
        for (int i = 0; i < 8; ++i) {
            float v = 0.25f * ap[i];
            unsigned h = bf16u(v);
            a0hi[kh][i] = (short)h;
            a0lo[kh][i] = (short)bf16u(v - __uint_as_float(h << 16));
        }
    }

    f32x4 w0[8];
    #pragma unroll
    for (int t = 0; t < 8; ++t) w0[t] = (f32x4){0.f, 0.f, 0.f, 0.f};
    #pragma unroll
    for (int t = 0; t < 8; ++t)
        #pragma unroll
        for (int kh = 0; kh < 2; ++kh) {
            short8 b = *(const short8*)(WoB + (size_t)(t * 2 + kh) * 512 + lane * 8);
            w0[t] = __builtin_amdgcn_mfma_f32_16x16x32_bf16(a0hi[kh], b, w0[t], 0, 0, 0);
            w0[t] = __builtin_amdgcn_mfma_f32_16x16x32_bf16(a0lo[kh], b, w0[t], 0, 0, 0);
        }
    #pragma unroll
    for (int s = 0; s < 5; ++s) {
        if (!__any(sp_c == s)) continue;
        short8 mk0 = (sp_c == s) ? x0f[0] : z8;
        short8 mk1 = (sp_c == s) ? x0f[1] : z8;
        #pragma unroll
        for (int t = 0; t < 8; ++t) {
            short8 b0 = *(const short8*)(WoB + (size_t)(16 + s * 16 + t * 2) * 512 + lane * 8);
            short8 b1 = *(const short8*)(WoB + (size_t)(16 + s * 16 + t * 2 + 1) * 512 + lane * 8);
            w0[t] = __builtin_amdgcn_mfma_f32_16x16x32_bf16(mk0, b0, w0[t], 0, 0, 0);
            w0[t] = __builtin_amdgcn_mfma_f32_16x16x32_bf16(mk1, b1, w0[t], 0, 0, 0);
        }
    }
    float gate[4][4];
    #pragma unroll
    for (int t = 0; t < 8; ++t)
        #pragma unroll
        for (int i = 0; i < 4; ++i) {
            float x = w0[t][i];
            float sv = x / (1.f + __expf(-x));
            if (t < 4) ldsOut[wv][4 * g + i][16 * t + c] = sv;
            else       gate[t - 4][i] = sv;
        }

    short8 x1f[3][2], a1hi[3][2], a1lo[3][2];
    #pragma unroll
    for (int j = 0; j < 3; ++j)
        #pragma unroll
        for (int kh = 0; kh < 2; ++kh) {
            x1f[j][kh] = *(const short8*)&xpk[(size_t)nc * 256 + (1 + j) * 64 + kh * 32 + g * 8];
            const float* ap = acc + (size_t)nc * 256 + 64 + 64 * j + kh * 32 + g * 8;
            #pragma unroll
            for (int i = 0; i < 8; ++i) {
                float v = 0.25f * ap[i];
                unsigned h = bf16u(v);
                a1hi[j][kh][i] = (short)h;
                a1lo[j][kh][i] = (short)bf16u(v - __uint_as_float(h << 16));
            }
        }

    f32x4 w1[3][4];
    #pragma unroll
    for (int j = 0; j < 3; ++j)
        #pragma unroll
        for (int t = 0; t < 4; ++t) w1[j][t] = (f32x4){0.f, 0.f, 0.f, 0.f};
    #pragma unroll
    for (int t = 0; t < 4; ++t)
        #pragma unroll
        for (int kh = 0; kh < 2; ++kh) {
            short8 b = *(const short8*)(WoB + (size_t)(96 + t * 2 + kh) * 512 + lane * 8);
            #pragma unroll
            for (int j = 0; j < 3; ++j) {
                w1[j][t] = __builtin_amdgcn_mfma_f32_16x16x32_bf16(a1hi[j][kh], b, w1[j][t], 0, 0, 0);
                w1[j][t] = __builtin_amdgcn_mfma_f32_16x16x32_bf16(a1lo[j][kh], b, w1[j][t], 0, 0, 0);
            }
        }
    #pragma unroll
    for (int s = 0; s < 5; ++s) {
        if (!__any(sp_c == s)) continue;
        short8 m1[3][2];
        #pragma unroll
        for (int j = 0; j < 3; ++j) {
            m1[j][0] = (sp_c == s) ? x1f[j][0] : z8;
            m1[j][1] = (sp_c == s) ? x1f[j][1] : z8;
        }
        #pragma unroll
        for (int t = 0; t < 4; ++t)
            #pragma unroll
            for (int kh = 0; kh < 2; ++kh) {
                short8 b = *(const short8*)(WoB + (size_t)(104 + s * 8 + t * 2 + kh) * 512 + lane * 8);
                #pragma unroll
                for (int j = 0; j < 3; ++j)
                    w1[j][t] = __builtin_amdgcn_mfma_f32_16x16x32_bf16(m1[j][kh], b, w1[j][t], 0, 0, 0);
            }
    }
    #pragma unroll
    for (int j = 0; j < 3; ++j)
        #pragma unroll
        for (int t = 0; t < 4; ++t)
            #pragma unroll
            for (int i = 0; i < 4; ++i)
                ldsOut[wv][4 * g + i][64 + (16 * t + c) * 3 + j] = w1[j][t][i] * gate[t][i];

    #pragma unroll 4
    for (int r = 0; r < 16; ++r) {
        int nn = n0 + r;
        if (nn < N)
            *(float4*)&out[(size_t)nn * 256 + lane * 4] =
                *(const float4*)&ldsOut[wv][r][lane * 4];
    }
}

// ---------------------------------------------------------------------------
extern "C" void kernel_launch(void* const* d_in, const int* in_sizes, int n_in,
                              void* d_out, int out_size, void* d_ws, size_t ws_size,
                              hipStream_t stream) {
    const float* vectors     = (const float*)d_in[0];
    const float* node_feats  = (const float*)d_in[1];
    const int*   node_specie = (const int*)d_in[2];
    const int*   senders     = (const int*)d_in[3];
    const int*   receivers   = (const int*)d_in[4];
    const float* W0_up       = (const float*)d_in[5];
    const float* W1_up       = (const float*)d_in[6];
    const float* Wm1         = (const float*)d_in[7];
    const float* Wm2         = (const float*)d_in[8];
    const float* Wm3         = (const float*)d_in[9];
    const float* Ws0         = (const float*)d_in[10];
    const float* Ws1         = (const float*)d_in[11];
    const float* Wd0         = (const float*)d_in[12];
    const float* Wd1         = (const float*)d_in[13];
    float* out = (float*)d_out;

    int E = in_sizes[0] / 3;
    int N = in_sizes[1] / 256;
    int nblk = (N + 1023) / 1024;

    char* wp = (char*)d_ws;
    uint2* ubf     = (uint2*)wp;                wp += (size_t)N * 64 * 8;
    float* acc     = (float*)wp;                wp += (size_t)N * 256 * 4;
    short* xpk     = (short*)wp;                wp += (size_t)N * 256 * 2;
    uint4* epackA  = (uint4*)wp;                wp += (size_t)(E + 16) * 16;
    float4* epackB = (float4*)wp;               wp += (size_t)(E + 16) * 16;
    unsigned short* wmix = (unsigned short*)wp; // only used on split path
    size_t wmix_bytes = (size_t)(E + 16) * 320 * 2;
    size_t base_used = (size_t)(wp - (char*)d_ws);
    size_t other_bytes = (4 + 8 + 40 + 144) * 512 * 2        // weight frags
                       + (size_t)(N) * 4 + (size_t)(N + 1) * 4
                       + (size_t)N * 4 + (size_t)(nblk + 1) * 4 + 256;
    bool use_split = (base_used + wmix_bytes + other_bytes) <= ws_size;
    if (use_split) wp += wmix_bytes;

    short* W1B    = (short*)wp;                 wp += 4 * 512 * 2;
    short* Wm2B   = (short*)wp;                 wp += 8 * 512 * 2;
    short* W3B    = (short*)wp;                 wp += 40 * 512 * 2;
    short* WoB    = (short*)wp;                 wp += 144 * 512 * 2;
    int*   cnt    = (int*)wp;                   wp += (size_t)N * 4;
    int*   offs   = (int*)wp;                   wp += (size_t)(N + 1) * 4;
    int*   cursor = (int*)wp;                   wp += (size_t)N * 4;
    int*   part   = (int*)wp;                   wp += (size_t)(nblk + 1) * 4;

    prep_kernel<<<80, 256, 0, stream>>>(
        Wm1, Wm2, Wm3, Wd0, Ws0, Wd1, Ws1, W1B, Wm2B, W3B, WoB, cnt, N);
    hist_kernel<<<1024, 256, 0, stream>>>(receivers, cnt, E);
    scan1_kernel<<<nblk, 256, 0, stream>>>(cnt, offs, part, N);
    scan23_kernel<<<nblk, 256, 0, stream>>>(offs, cursor, part, nblk, N);
    const int FPB = 1024;
    fpnu_kernel<<<FPB + (N + 3) / 4, 256, 0, stream>>>(
        vectors, senders, receivers, cursor, epackA, epackB,
        node_feats, W0_up, W1_up, ubf, xpk, E, N, FPB);

    if (use_split) {
        mlp_kernel<<<768, 256, 0, stream>>>(
            epackA, W1B, Wm2B, W3B, wmix, E, 768 * 4);
        gather_kernel<<<(N + 3) / 4, 256, 0, stream>>>(
            epackB, offs, ubf, wmix, acc, N);
    } else {
        edge_kernel<<<512, 256, 0, stream>>>(
            epackA, epackB, offs, ubf, W1B, Wm2B, W3B, acc, N, 512 * 4);
    }

    int ngroups = (N + 15) / 16;
    node_out_kernel<<<(ngroups + 3) / 4, 256, 0, stream>>>(
        acc, xpk, node_specie, WoB, out, N);
}

// Round 17
// 236.788 us; speedup vs baseline: 2.2817x; 1.0721x over previous
//
#include <hip/hip_runtime.h>
#include <hip/hip_bf16.h>

typedef __attribute__((ext_vector_type(8))) short short8;
typedef __attribute__((ext_vector_type(4))) float f32x4;

__device__ __forceinline__ unsigned bf16u(float x) {
    unsigned u = __float_as_uint(x);
    return (u + 0x7fffu + ((u >> 16) & 1u)) >> 16;
}
__device__ __forceinline__ short bf16s(float x) { return (short)bf16u(x); }

// ---------------------------------------------------------------------------
// Prep (merged): zero padded cnt + pack ALL weights into MFMA B-fragments.
// cnt is padded: one counter per 64B cacheline (stride 16 ints).
// ---------------------------------------------------------------------------
__global__ __launch_bounds__(256) void prep_kernel(
    const float* __restrict__ Wm1, const float* __restrict__ Wm2,
    const float* __restrict__ Wm3,
    const float* __restrict__ Wd0, const float* __restrict__ Ws0,
    const float* __restrict__ Wd1, const float* __restrict__ Ws1,
    short* __restrict__ W1B, short* __restrict__ Wm2B, short* __restrict__ W3B,
    short* __restrict__ WoB, int* __restrict__ cnt, int N)
{
    const int tid = blockIdx.x * 256 + threadIdx.x;
    const int nth = gridDim.x * 256;

    for (int i = tid; i < N * 16; i += nth) cnt[i] = 0;

    for (int idx = tid; idx < 52 * 64; idx += nth) {
        int l = idx & 63, f = idx >> 6;
        int g = l >> 4, c = l & 15;
        short8 v;
        if (f < 4) {
            #pragma unroll
            for (int i = 0; i < 8; ++i)
                v[i] = (g == 0) ? bf16s(Wm1[(size_t)i * 64 + f * 16 + c]) : (short)0;
            *(short8*)(W1B + (size_t)f * 512 + l * 8) = v;
        } else if (f < 12) {
            int f2 = f - 4, t = f2 >> 1, kh = f2 & 1;
            #pragma unroll
            for (int i = 0; i < 8; ++i)
                v[i] = bf16s(Wm2[(size_t)(kh * 32 + g * 8 + i) * 64 + t * 16 + c]);
            *(short8*)(Wm2B + (size_t)f2 * 512 + l * 8) = v;
        } else {
            int f3 = f - 12, t = f3 >> 1, kh = f3 & 1;
            #pragma unroll
            for (int i = 0; i < 8; ++i)
                v[i] = bf16s(Wm3[(size_t)(kh * 32 + g * 8 + i) * 320 + t * 16 + c]);
            *(short8*)(W3B + (size_t)f3 * 512 + l * 8) = v;
        }
    }

    for (int idx = tid; idx < 144 * 64; idx += nth) {
        int l = idx & 63, f = idx >> 6;
        int g = l >> 4, c = l & 15;
        short8 v;
        if (f < 16) {
            int t = f >> 1, kh = f & 1;
            #pragma unroll
            for (int i = 0; i < 8; ++i)
                v[i] = bf16s(Wd0[(size_t)(kh * 32 + g * 8 + i) * 128 + t * 16 + c]);
        } else if (f < 96) {
            int s = (f - 16) >> 4, r = (f - 16) & 15, t = r >> 1, kh = r & 1;
            #pragma unroll
            for (int i = 0; i < 8; ++i)
                v[i] = bf16s(Ws0[((size_t)s * 64 + kh * 32 + g * 8 + i) * 128 + t * 16 + c]);
        } else if (f < 104) {
            int r = f - 96, t = r >> 1, kh = r & 1;
            #pragma unroll
            for (int i = 0; i < 8; ++i)
                v[i] = bf16s(Wd1[(size_t)(kh * 32 + g * 8 + i) * 64 + t * 16 + c]);
        } else {
            int s = (f - 104) >> 3, r = (f - 104) & 7, t = r >> 1, kh = r & 1;
            #pragma unroll
            for (int i = 0; i < 8; ++i)
                v[i] = bf16s(Ws1[((size_t)s * 64 + kh * 32 + g * 8 + i) * 64 + t * 16 + c]);
        }
        *(short8*)(WoB + (size_t)f * 512 + l * 8) = v;
    }
}

// ---------------------------------------------------------------------------
// Rank pass: the ONLY atomic pass. rank[i] = arrival rank within receiver
// bucket; padded counters (64B apart) kill false sharing.
// ---------------------------------------------------------------------------
__global__ __launch_bounds__(256) void rank_kernel(
    const int* __restrict__ receivers, int* __restrict__ cnt,
    int* __restrict__ rank, int E)
{
    int i = blockIdx.x * 256 + threadIdx.x;
    int stride = gridDim.x * 256;
    for (; i < E; i += stride)
        rank[i] = atomicAdd(&cnt[receivers[i] << 4], 1);
}

__global__ __launch_bounds__(256) void scan1_kernel(
    const int* __restrict__ cnt, int* __restrict__ offs,
    int* __restrict__ part, int N)
{
    __shared__ int a_[256], b_[256];
    const int b = blockIdx.x, t = threadIdx.x;
    const int base = b * 1024 + t * 4;
    int v[4];
    #pragma unroll
    for (int k = 0; k < 4; ++k)
        v[k] = (base + k < N) ? cnt[(size_t)(base + k) << 4] : 0;
    int sum = v[0] + v[1] + v[2] + v[3];
    a_[t] = sum;
    __syncthreads();
    int* src = a_; int* dst = b_;
    for (int off = 1; off < 256; off <<= 1) {
        dst[t] = src[t] + ((t >= off) ? src[t - off] : 0);
        __syncthreads();
        int* tmp = src; src = dst; dst = tmp;
    }
    int excl = src[t] - sum;
    if (t == 0) part[b] = src[255];
    int run = excl;
    #pragma unroll
    for (int k = 0; k < 4; ++k) {
        if (base + k < N) offs[base + k] = run;
        run += v[k];
    }
}

// scan2+scan3 merged: each block redundantly scans the small partials array,
// adds its base. Block 0 writes offs[N].
__global__ __launch_bounds__(256) void scan23_kernel(
    int* __restrict__ offs, const int* __restrict__ part, int nblk, int N)
{
    __shared__ int base_s, total_s;
    const int b = blockIdx.x, t = threadIdx.x;
    if (t == 0) {
        int s = 0, tot = 0;
        for (int i = 0; i < nblk; ++i) {
            if (i < b) s += part[i];
            tot += part[i];
        }
        base_s = s; total_s = tot;
    }
    __syncthreads();
    const int add = base_s;
    const int base = b * 1024 + t * 4;
    #pragma unroll
    for (int k = 0; k < 4; ++k) {
        int i = base + k;
        if (i < N) offs[i] += add;
    }
    if (b == 0 && t == 0) offs[N] = total_s;
}

// ---------------------------------------------------------------------------
// Merged fill_pack + node_up. Pack pass is now ATOMIC-FREE:
// pos = offs[receiver] + rank[i]  (rank from the single atomic pass).
// ---------------------------------------------------------------------------
__global__ __launch_bounds__(256) void fpnu_kernel(
    const float* __restrict__ vectors, const int* __restrict__ senders,
    const int* __restrict__ receivers, const int* __restrict__ offs,
    const int* __restrict__ rank,
    uint4* __restrict__ epackA, float4* __restrict__ epackB,
    const float* __restrict__ node_feats, const float* __restrict__ W0_up,
    const float* __restrict__ W1_up, uint2* __restrict__ ubf,
    short* __restrict__ xpk, int E, int N, int FPB)
{
    if (blockIdx.x < FPB) {
        int i = blockIdx.x * 256 + threadIdx.x;
        int stride = FPB * 256;
        for (; i < E; i += stride) {
            int pos = offs[receivers[i]] + rank[i];
            float vx = vectors[3 * (size_t)i + 0];
            float vy = vectors[3 * (size_t)i + 1];
            float vz = vectors[3 * (size_t)i + 2];
            float r = sqrtf(vx * vx + vy * vy + vz * vz);
            float ir = (r != 0.f) ? 1.f / r : 0.f;
            float ang = r * 0.6283185307179586f;   // pi/5
            float s1, c1;
            __sincosf(ang, &s1, &c1);
            float tc = 2.f * c1;
            float sb = s1, sp = 0.f;
            float coef = 0.6324555320336759f * ir;
            unsigned bw[4];
            #pragma unroll
            for (int h = 0; h < 4; ++h) {
                unsigned lo = bf16u(sb * coef);
                float nx = tc * sb - sp; sp = sb; sb = nx;
                unsigned hi = bf16u(sb * coef);
                nx = tc * sb - sp; sp = sb; sb = nx;
                bw[h] = lo | (hi << 16);
            }
            epackA[pos] = make_uint4(bw[0], bw[1], bw[2], bw[3]);
            epackB[pos] = make_float4(vx * ir, vy * ir, vz * ir,
                                      __int_as_float(senders[i]));
        }
    } else {
        int nb = (blockIdx.x - FPB) * 4 + (threadIdx.x >> 6);
        int d  = threadIdx.x & 63;
        if (nb >= N) return;
        const float* nf = node_feats + (size_t)nb * 256;
        float a0 = 0.f, ax = 0.f, ay = 0.f, az = 0.f;
        #pragma unroll 4
        for (int cc = 0; cc < 64; ++cc) {
            float w0 = W0_up[cc * 64 + d];
            float w1 = W1_up[cc * 64 + d];
            a0 += nf[cc] * w0;
            ax += nf[64 + cc * 3 + 0] * w1;
            ay += nf[64 + cc * 3 + 1] * w1;
            az += nf[64 + cc * 3 + 2] * w1;
        }
        ubf[(size_t)nb * 64 + d] = make_uint2(bf16u(a0) | (bf16u(ax) << 16),
                                              bf16u(ay) | (bf16u(az) << 16));
        short* xp = xpk + (size_t)nb * 256;
        xp[d]       = bf16s(nf[d]);
        xp[64 + d]  = bf16s(nf[64 + d * 3 + 0]);
        xp[128 + d] = bf16s(nf[64 + d * 3 + 1]);
        xp[192 + d] = bf16s(nf[64 + d * 3 + 2]);
    }
}

// ---------------------------------------------------------------------------
// SPLIT kernel A: dense MLP over flat 16-row CSR windows -> wmix bf16.
// ---------------------------------------------------------------------------
__global__ __launch_bounds__(256) void mlp_kernel(
    const uint4* __restrict__ epackA,
    const short* __restrict__ W1B, const short* __restrict__ Wm2B,
    const short* __restrict__ W3B, unsigned short* __restrict__ wmix,
    int P, int nwaves)
{
    __shared__ __align__(16) short ldsW3[40 * 512];
    __shared__ __align__(16) short ldsH[4][1024];

    {
        const short8* src = (const short8*)W3B;
        short8* dst = (short8*)ldsW3;
        for (int i = threadIdx.x; i < 2560; i += 256) dst[i] = src[i];
    }
    __syncthreads();

    const int lane = threadIdx.x & 63;
    const int wv   = threadIdx.x >> 6;
    const int gw   = blockIdx.x * 4 + wv;
    const int c = lane & 15, g = lane >> 4;
    const int nwin = (P + 15) >> 4;

    for (int w = gw; w < nwin; w += nwaves) {
        const int p0 = w << 4;

        short8 basisA = {0, 0, 0, 0, 0, 0, 0, 0};
        if (lane < 16) {
            uint4 ba = epackA[p0 + lane];   // tail rows garbage but never stored
            union { uint4 u4v; short8 s8; } cv;
            cv.u4v = ba;
            basisA = cv.s8;
        }

        #pragma unroll
        for (int t = 0; t < 4; ++t) {
            f32x4 h = {0.f, 0.f, 0.f, 0.f};
            short8 bf = *(const short8*)(W1B + (size_t)t * 512 + lane * 8);
            h = __builtin_amdgcn_mfma_f32_16x16x32_bf16(basisA, bf, h, 0, 0, 0);
            #pragma unroll
            for (int i = 0; i < 4; ++i) {
                float x = h[i];
                float h1 = x / (1.f + __expf(-x));
                int row = 4 * g + i;
                ldsH[wv][row * 64 + ((16 * t + c) ^ ((row & 7) << 3))] = bf16s(h1);
            }
        }
        short8 h1f0 = *(const short8*)&ldsH[wv][c * 64 + ((g * 8) ^ ((c & 7) << 3))];
        short8 h1f1 = *(const short8*)&ldsH[wv][c * 64 + ((32 + g * 8) ^ ((c & 7) << 3))];

        #pragma unroll
        for (int t = 0; t < 4; ++t) {
            f32x4 h = {0.f, 0.f, 0.f, 0.f};
            short8 b0 = *(const short8*)(Wm2B + (size_t)(t * 2) * 512 + lane * 8);
            short8 b1 = *(const short8*)(Wm2B + (size_t)(t * 2 + 1) * 512 + lane * 8);
            h = __builtin_amdgcn_mfma_f32_16x16x32_bf16(h1f0, b0, h, 0, 0, 0);
            h = __builtin_amdgcn_mfma_f32_16x16x32_bf16(h1f1, b1, h, 0, 0, 0);
            #pragma unroll
            for (int i = 0; i < 4; ++i) {
                float x = h[i];
                float h2 = x / (1.f + __expf(-x));
                int row = 4 * g + i;
                ldsH[wv][row * 64 + ((16 * t + c) ^ ((row & 7) << 3))] = bf16s(h2);
            }
        }
        short8 h2f0 = *(const short8*)&ldsH[wv][c * 64 + ((g * 8) ^ ((c & 7) << 3))];
        short8 h2f1 = *(const short8*)&ldsH[wv][c * 64 + ((32 + g * 8) ^ ((c & 7) << 3))];

        size_t rowOfs[4];
        bool ok[4];
        #pragma unroll
        for (int i = 0; i < 4; ++i) {
            int row = p0 + 4 * g + i;
            ok[i] = (row < P);
            rowOfs[i] = (size_t)row * 320;
        }
        #pragma unroll
        for (int t = 0; t < 20; ++t) {
            f32x4 wq = {0.f, 0.f, 0.f, 0.f};
            short8 b0 = *(const short8*)(ldsW3 + (size_t)(t * 2) * 512 + lane * 8);
            short8 b1 = *(const short8*)(ldsW3 + (size_t)(t * 2 + 1) * 512 + lane * 8);
            wq = __builtin_amdgcn_mfma_f32_16x16x32_bf16(h2f0, b0, wq, 0, 0, 0);
            wq = __builtin_amdgcn_mfma_f32_16x16x32_bf16(h2f1, b1, wq, 0, 0, 0);
            const int col = (t >> 2) * 64 + (t & 3) * 16 + c;
            #pragma unroll
            for (int i = 0; i < 4; ++i)
                if (ok[i]) wmix[rowOfs[i] + col] = (unsigned short)bf16u(wq[i]);
        }
    }
}

// ---------------------------------------------------------------------------
// SPLIT kernel B: gather + messages + accumulate. Wave per node, lane=d.
// ---------------------------------------------------------------------------
__global__ __launch_bounds__(256) void gather_kernel(
    const float4* __restrict__ epackB, const int* __restrict__ offs,
    const uint2* __restrict__ ubf, const unsigned short* __restrict__ wmix,
    float* __restrict__ acc, int N)
{
    const int lane = threadIdx.x & 63;
    const int n = blockIdx.x * 4 + (threadIdx.x >> 6);
    if (n >= N) return;

    const int beg = offs[n], end = offs[n + 1];
    float a0 = 0.f, a1x = 0.f, a1y = 0.f, a1z = 0.f;

    #pragma unroll 2
    for (int pos = beg; pos < end; ++pos) {
        float4 mb = epackB[pos];
        int snd = __float_as_int(mb.w);
        uint2 mu = ubf[(size_t)snd * 64 + lane];
        const unsigned short* wr = wmix + (size_t)pos * 320;
        float w00  = __uint_as_float((unsigned)wr[lane]        << 16);
        float w01  = __uint_as_float((unsigned)wr[64 + lane]   << 16);
        float w10  = __uint_as_float((unsigned)wr[128 + lane]  << 16);
        float w11d = __uint_as_float((unsigned)wr[192 + lane]  << 16);
        float w11c = __uint_as_float((unsigned)wr[256 + lane]  << 16);
        float m0  = __uint_as_float(mu.x << 16);
        float m1x = __uint_as_float(mu.x & 0xffff0000u);
        float m1y = __uint_as_float(mu.y << 16);
        float m1z = __uint_as_float(mu.y & 0xffff0000u);

        float dotv = m1x * mb.x + m1y * mb.y + m1z * mb.z;
        a0 += w00 * m0 + w11d * dotv;
        float wm = w01 * m0;
        a1x += wm * mb.x + w10 * m1x + w11c * (m1y * mb.z - m1z * mb.y);
        a1y += wm * mb.y + w10 * m1y + w11c * (m1z * mb.x - m1x * mb.z);
        a1z += wm * mb.z + w10 * m1z + w11c * (m1x * mb.y - m1y * mb.x);
    }

    float* ar = acc + (size_t)n * 256;
    ar[lane]       = a0;
    ar[64 + lane]  = a1x;
    ar[128 + lane] = a1y;
    ar[192 + lane] = a1z;
}

// ---------------------------------------------------------------------------
// FALLBACK: fused edge kernel (R13 version; used when ws too small for wmix)
// ---------------------------------------------------------------------------
__global__ __launch_bounds__(256) void edge_kernel(
    const uint4* __restrict__ epackA, const float4* __restrict__ epackB,
    const int* __restrict__ offs, const uint2* __restrict__ ubf,
    const short* __restrict__ W1B, const short* __restrict__ Wm2B,
    const short* __restrict__ W3B, float* __restrict__ acc,
    int N, int nwaves)
{
    __shared__ __align__(16) short ldsW3[40 * 512];
    __shared__ __align__(16) short ldsH[4][1024];
    __shared__ __align__(16) float ldsMeta[4][16][4];

    {
        const short8* src = (const short8*)W3B;
        short8* dst = (short8*)ldsW3;
        for (int i = threadIdx.x; i < 2560; i += 256) dst[i] = src[i];
    }
    __syncthreads();

    const int lane = threadIdx.x & 63;
    const int wv   = threadIdx.x >> 6;
    const int gw   = blockIdx.x * 4 + wv;
    const int c = lane & 15, g = lane >> 4;

    for (int n = gw; n < N; n += nwaves) {
        float a0q[4]  = {0.f, 0.f, 0.f, 0.f};
        float a1xq[4] = {0.f, 0.f, 0.f, 0.f};
        float a1yq[4] = {0.f, 0.f, 0.f, 0.f};
        float a1zq[4] = {0.f, 0.f, 0.f, 0.f};
        const int beg = offs[n], end = offs[n + 1];

        for (int p0 = beg; p0 < end; p0 += 16) {
            const int m = end - p0;
            short8 basisA = {0, 0, 0, 0, 0, 0, 0, 0};
            if (lane < 16) {
                uint4 ba = epackA[p0 + lane];
                float4 mb = epackB[p0 + lane];
                if (lane >= m) {
                    ba = make_uint4(0u, 0u, 0u, 0u);
                    mb = make_float4(0.f, 0.f, 0.f, __int_as_float(0));
                }
                union { uint4 u4v; short8 s8; } cv;
                cv.u4v = ba;
                basisA = cv.s8;
                *(float4*)&ldsMeta[wv][lane][0] = mb;
            }
            float Yx[4], Yy[4], Yz[4];
            int snd[4];
            #pragma unroll
            for (int i = 0; i < 4; ++i) {
                float4 mt = *(const float4*)&ldsMeta[wv][4 * g + i][0];
                Yx[i] = mt.x; Yy[i] = mt.y; Yz[i] = mt.z;
                snd[i] = __float_as_int(mt.w);
            }

#define PFETCH(Q, MV)                                                       \
            _Pragma("unroll")                                               \
            for (int i = 0; i < 4; ++i)                                     \
                MV[i] = ubf[(size_t)snd[i] * 64 + 16 * (Q) + c];

#define COMPQ(Q, MV)                                                        \
        {                                                                   \
            float M0[4], M1X[4], M1Y[4], M1Z[4];                            \
            _Pragma("unroll")                                               \
            for (int i = 0; i < 4; ++i) {                                   \
                M0[i]  = __uint_as_float(MV[i].x << 16);                    \
                M1X[i] = __uint_as_float(MV[i].x & 0xffff0000u);            \
                M1Y[i] = __uint_as_float(MV[i].y << 16);                    \
                M1Z[i] = __uint_as_float(MV[i].y & 0xffff0000u);            \
            }                                                               \
            _Pragma("unroll")                                               \
            for (int p = 0; p < 5; ++p) {                                   \
                const int t = 4 * p + (Q);                                  \
                f32x4 w = {0.f, 0.f, 0.f, 0.f};                             \
                short8 b0 = *(const short8*)(ldsW3 + (size_t)(t * 2) * 512 + lane * 8);     \
                short8 b1 = *(const short8*)(ldsW3 + (size_t)(t * 2 + 1) * 512 + lane * 8); \
                w = __builtin_amdgcn_mfma_f32_16x16x32_bf16(h2f0, b0, w, 0, 0, 0);          \
                w = __builtin_amdgcn_mfma_f32_16x16x32_bf16(h2f1, b1, w, 0, 0, 0);          \
                _Pragma("unroll")                                           \
                for (int i = 0; i < 4; ++i) {                               \
                    float wv_ = w[i];                                       \
                    if (p == 0) {                                           \
                        a0q[Q] += wv_ * M0[i];                              \
                    } else if (p == 1) {                                    \
                        float tt = wv_ * M0[i];                             \
                        a1xq[Q] += tt * Yx[i];                              \
                        a1yq[Q] += tt * Yy[i];                              \
                        a1zq[Q] += tt * Yz[i];                              \
                    } else if (p == 2) {                                    \
                        a1xq[Q] += wv_ * M1X[i];                            \
                        a1yq[Q] += wv_ * M1Y[i];                            \
                        a1zq[Q] += wv_ * M1Z[i];                            \
                    } else if (p == 3) {                                    \
                        a0q[Q] += wv_ * (M1X[i] * Yx[i] + M1Y[i] * Yy[i] + M1Z[i] * Yz[i]); \
                    } else {                                                \
                        a1xq[Q] += wv_ * (M1Y[i] * Yz[i] - M1Z[i] * Yy[i]); \
                        a1yq[Q] += wv_ * (M1Z[i] * Yx[i] - M1X[i] * Yz[i]); \
                        a1zq[Q] += wv_ * (M1X[i] * Yy[i] - M1Y[i] * Yx[i]); \
                    }                                                       \
                }                                                           \
            }                                                               \
        }

            uint2 mA[4], mB[4];
            PFETCH(0, mA);
            PFETCH(1, mB);
            __builtin_amdgcn_sched_barrier(0);

            #pragma unroll
            for (int t = 0; t < 4; ++t) {
                f32x4 h = {0.f, 0.f, 0.f, 0.f};
                short8 bf = *(const short8*)(W1B + (size_t)t * 512 + lane * 8);
                h = __builtin_amdgcn_mfma_f32_16x16x32_bf16(basisA, bf, h, 0, 0, 0);
                #pragma unroll
                for (int i = 0; i < 4; ++i) {
                    float x = h[i];
                    float h1 = x / (1.f + __expf(-x));
                    int row = 4 * g + i;
                    ldsH[wv][row * 64 + ((16 * t + c) ^ ((row & 7) << 3))] = bf16s(h1);
                }
            }
            short8 h1f0 = *(const short8*)&ldsH[wv][c * 64 + ((g * 8) ^ ((c & 7) << 3))];
            short8 h1f1 = *(const short8*)&ldsH[wv][c * 64 + ((32 + g * 8) ^ ((c & 7) << 3))];

            #pragma unroll
            for (int t = 0; t < 4; ++t) {
                f32x4 h = {0.f, 0.f, 0.f, 0.f};
                short8 b0 = *(const short8*)(Wm2B + (size_t)(t * 2) * 512 + lane * 8);
                short8 b1 = *(const short8*)(Wm2B + (size_t)(t * 2 + 1) * 512 + lane * 8);
                h = __builtin_amdgcn_mfma_f32_16x16x32_bf16(h1f0, b0, h, 0, 0, 0);
                h = __builtin_amdgcn_mfma_f32_16x16x32_bf16(h1f1, b1, h, 0, 0, 0);
                #pragma unroll
                for (int i = 0; i < 4; ++i) {
                    float x = h[i];
                    float h2 = x / (1.f + __expf(-x));
                    int row = 4 * g + i;
                    ldsH[wv][row * 64 + ((16 * t + c) ^ ((row & 7) << 3))] = bf16s(h2);
                }
            }
            short8 h2f0 = *(const short8*)&ldsH[wv][c * 64 + ((g * 8) ^ ((c & 7) << 3))];
            short8 h2f1 = *(const short8*)&ldsH[wv][c * 64 + ((32 + g * 8) ^ ((c & 7) << 3))];

            COMPQ(0, mA);
            __builtin_amdgcn_sched_barrier(0);
            PFETCH(2, mA);
            COMPQ(1, mB);
            __builtin_amdgcn_sched_barrier(0);
            PFETCH(3, mB);
            COMPQ(2, mA);
            __builtin_amdgcn_sched_barrier(0);
            COMPQ(3, mB);
#undef PFETCH
#undef COMPQ
        }

        #pragma unroll
        for (int q = 0; q < 4; ++q) {
            a0q[q]  += __shfl_xor(a0q[q], 16);  a0q[q]  += __shfl_xor(a0q[q], 32);
            a1xq[q] += __shfl_xor(a1xq[q], 16); a1xq[q] += __shfl_xor(a1xq[q], 32);
            a1yq[q] += __shfl_xor(a1yq[q], 16); a1yq[q] += __shfl_xor(a1yq[q], 32);
            a1zq[q] += __shfl_xor(a1zq[q], 16); a1zq[q] += __shfl_xor(a1zq[q], 32);
        }
        if (lane < 16) {
            float* ar = acc + (size_t)n * 256;
            #pragma unroll
            for (int q = 0; q < 4; ++q) {
                ar[16 * q + lane]       = a0q[q];
                ar[64 + 16 * q + lane]  = a1xq[q];
                ar[128 + 16 * q + lane] = a1yq[q];
                ar[192 + 16 * q + lane] = a1zq[q];
            }
        }
    }
}

// ---------------------------------------------------------------------------
// Node epilogue: MFMA masked-species dense GEMM. (unchanged)
// ---------------------------------------------------------------------------
__global__ __launch_bounds__(256) void node_out_kernel(
    const float* __restrict__ acc, const short* __restrict__ xpk,
    const int* __restrict__ node_specie, const short* __restrict__ WoB,
    float* __restrict__ out, int N)
{
    __shared__ float ldsOut[4][16][256];
    const int lane = threadIdx.x & 63;
    const int wv   = threadIdx.x >> 6;
    const int c = lane & 15, g = lane >> 4;
    const int n0 = (blockIdx.x * 4 + wv) * 16;
    if (n0 >= N) return;

    const int nc = min(n0 + c, N - 1);
    const int sp_c = node_specie[nc];
    const short8 z8 = {0, 0, 0, 0, 0, 0, 0, 0};

    short8 x0f[2], a0hi[2], a0lo[2];
    #pragma unroll
    for (int kh = 0; kh < 2; ++kh) {
        x0f[kh] = *(const short8*)&xpk[(size_t)nc * 256 + kh * 32 + g * 8];
        const float* ap = acc + (size_t)nc * 256 + kh * 32 + g * 8;
        #pragma unroll
        for (int i = 0; i < 8; ++i) {
            float v = 0.25f * ap[i];
            unsigned h = bf16u(v);
            a0hi[kh][i] = (short)h;
            a0lo[kh][i] = (short)bf16u(v - __uint_as_float(h << 16));
        }
    }

    f32x4 w0[8];
    #pragma unroll
    for (int t = 0; t < 8; ++t) w0[t] = (f32x4){0.f, 0.f, 0.f, 0.f};
    #pragma unroll
    for (int t = 0; t < 8; ++t)
        #pragma unroll
        for (int kh = 0; kh < 2; ++kh) {
            short8 b = *(const short8*)(WoB + (size_t)(t * 2 + kh) * 512 + lane * 8);
            w0[t] = __builtin_amdgcn_mfma_f32_16x16x32_bf16(a0hi[kh], b, w0[t], 0, 0, 0);
            w0[t] = __builtin_amdgcn_mfma_f32_16x16x32_bf16(a0lo[kh], b, w0[t], 0, 0, 0);
        }
    #pragma unroll
    for (int s = 0; s < 5; ++s) {
        if (!__any(sp_c == s)) continue;
        short8 mk0 = (sp_c == s) ? x0f[0] : z8;
        short8 mk1 = (sp_c == s) ? x0f[1] : z8;
        #pragma unroll
        for (int t = 0; t < 8; ++t) {
            short8 b0 = *(const short8*)(WoB + (size_t)(16 + s * 16 + t * 2) * 512 + lane * 8);
            short8 b1 = *(const short8*)(WoB + (size_t)(16 + s * 16 + t * 2 + 1) * 512 + lane * 8);
            w0[t] = __builtin_amdgcn_mfma_f32_16x16x32_bf16(mk0, b0, w0[t], 0, 0, 0);
            w0[t] = __builtin_amdgcn_mfma_f32_16x16x32_bf16(mk1, b1, w0[t], 0, 0, 0);
        }
    }
    float gate[4][4];
    #pragma unroll
    for (int t = 0; t < 8; ++t)
        #pragma unroll
        for (int i = 0; i < 4; ++i) {
            float x = w0[t][i];
            float sv = x / (1.f + __expf(-x));
            if (t < 4) ldsOut[wv][4 * g + i][16 * t + c] = sv;
            else       gate[t - 4][i] = sv;
        }

    short8 x1f[3][2], a1hi[3][2], a1lo[3][2];
    #pragma unroll
    for (int j = 0; j < 3; ++j)
        #pragma unroll
        for (int kh = 0; kh < 2; ++kh) {
            x1f[j][kh] = *(const short8*)&xpk[(size_t)nc * 256 + (1 + j) * 64 + kh * 32 + g * 8];
            const float* ap = acc + (size_t)nc * 256 + 64 + 64 * j + kh * 32 + g * 8;
            #pragma unroll
            for (int i = 0; i < 8; ++i) {
                float v = 0.25f * ap[i];
                unsigned h = bf16u(v);
                a1hi[j][kh][i] = (short)h;
                a1lo[j][kh][i] = (short)bf16u(v - __uint_as_float(h << 16));
            }
        }

    f32x4 w1[3][4];
    #pragma unroll
    for (int j = 0; j < 3; ++j)
        #pragma unroll
        for (int t = 0; t < 4; ++t) w1[j][t] = (f32x4){0.f, 0.f, 0.f, 0.f};
    #pragma unroll
    for (int t = 0; t < 4; ++t)
        #pragma unroll
        for (int kh = 0; kh < 2; ++kh) {
            short8 b = *(const short8*)(WoB + (size_t)(96 + t * 2 + kh) * 512 + lane * 8);
            #pragma unroll
            for (int j = 0; j < 3; ++j) {
                w1[j][t] = __builtin_amdgcn_mfma_f32_16x16x32_bf16(a1hi[j][kh], b, w1[j][t], 0, 0, 0);
                w1[j][t] = __builtin_amdgcn_mfma_f32_16x16x32_bf16(a1lo[j][kh], b, w1[j][t], 0, 0, 0);
            }
        }
    #pragma unroll
    for (int s = 0; s < 5; ++s) {
        if (!__any(sp_c == s)) continue;
        short8 m1[3][2];
        #pragma unroll
        for (int j = 0; j < 3; ++j) {
            m1[j][0] = (sp_c == s) ? x1f[j][0] : z8;
            m1[j][1] = (sp_c == s) ? x1f[j][1] : z8;
        }
        #pragma unroll
        for (int t = 0; t < 4; ++t)
            #pragma unroll
            for (int kh = 0; kh < 2; ++kh) {
                short8 b = *(const short8*)(WoB + (size_t)(104 + s * 8 + t * 2 + kh) * 512 + lane * 8);
                #pragma unroll
                for (int j = 0; j < 3; ++j)
                    w1[j][t] = __builtin_amdgcn_mfma_f32_16x16x32_bf16(m1[j][kh], b, w1[j][t], 0, 0, 0);
            }
    }
    #pragma unroll
    for (int j = 0; j < 3; ++j)
        #pragma unroll
        for (int t = 0; t < 4; ++t)
            #pragma unroll
            for (int i = 0; i < 4; ++i)
                ldsOut[wv][4 * g + i][64 + (16 * t + c) * 3 + j] = w1[j][t][i] * gate[t][i];

    #pragma unroll 4
    for (int r = 0; r < 16; ++r) {
        int nn = n0 + r;
        if (nn < N)
            *(float4*)&out[(size_t)nn * 256 + lane * 4] =
                *(const float4*)&ldsOut[wv][r][lane * 4];
    }
}

// ---------------------------------------------------------------------------
extern "C" void kernel_launch(void* const* d_in, const int* in_sizes, int n_in,
                              void* d_out, int out_size, void* d_ws, size_t ws_size,
                              hipStream_t stream) {
    const float* vectors     = (const float*)d_in[0];
    const float* node_feats  = (const float*)d_in[1];
    const int*   node_specie = (const int*)d_in[2];
    const int*   senders     = (const int*)d_in[3];
    const int*   receivers   = (const int*)d_in[4];
    const float* W0_up       = (const float*)d_in[5];
    const float* W1_up       = (const float*)d_in[6];
    const float* Wm1         = (const float*)d_in[7];
    const float* Wm2         = (const float*)d_in[8];
    const float* Wm3         = (const float*)d_in[9];
    const float* Ws0         = (const float*)d_in[10];
    const float* Ws1         = (const float*)d_in[11];
    const float* Wd0         = (const float*)d_in[12];
    const float* Wd1         = (const float*)d_in[13];
    float* out = (float*)d_out;

    int E = in_sizes[0] / 3;
    int N = in_sizes[1] / 256;
    int nblk = (N + 1023) / 1024;

    char* wp = (char*)d_ws;
    uint2* ubf     = (uint2*)wp;                wp += (size_t)N * 64 * 8;
    float* acc     = (float*)wp;                wp += (size_t)N * 256 * 4;
    short* xpk     = (short*)wp;                wp += (size_t)N * 256 * 2;
    uint4* epackA  = (uint4*)wp;                wp += (size_t)(E + 16) * 16;
    float4* epackB = (float4*)wp;               wp += (size_t)(E + 16) * 16;
    unsigned short* wmix = (unsigned short*)wp; // only used on split path
    size_t wmix_bytes = (size_t)(E + 16) * 320 * 2;
    size_t base_used = (size_t)(wp - (char*)d_ws);
    size_t other_bytes = (4 + 8 + 40 + 144) * 512 * 2
                       + (size_t)N * 16 * 4             // padded cnt
                       + (size_t)(N + 1) * 4            // offs
                       + (size_t)E * 4                  // rank
                       + (size_t)(nblk + 1) * 4 + 256;
    bool use_split = (base_used + wmix_bytes + other_bytes) <= ws_size;
    if (use_split) wp += wmix_bytes;

    short* W1B    = (short*)wp;                 wp += 4 * 512 * 2;
    short* Wm2B   = (short*)wp;                 wp += 8 * 512 * 2;
    short* W3B    = (short*)wp;                 wp += 40 * 512 * 2;
    short* WoB    = (short*)wp;                 wp += 144 * 512 * 2;
    int*   cnt    = (int*)wp;                   wp += (size_t)N * 16 * 4;   // padded
    int*   offs   = (int*)wp;                   wp += (size_t)(N + 1) * 4;
    int*   rank   = (int*)wp;                   wp += (size_t)E * 4;
    int*   part   = (int*)wp;                   wp += (size_t)(nblk + 1) * 4;

    prep_kernel<<<80, 256, 0, stream>>>(
        Wm1, Wm2, Wm3, Wd0, Ws0, Wd1, Ws1, W1B, Wm2B, W3B, WoB, cnt, N);
    rank_kernel<<<1024, 256, 0, stream>>>(receivers, cnt, rank, E);
    scan1_kernel<<<nblk, 256, 0, stream>>>(cnt, offs, part, N);
    scan23_kernel<<<nblk, 256, 0, stream>>>(offs, part, nblk, N);
    const int FPB = 1024;
    fpnu_kernel<<<FPB + (N + 3) / 4, 256, 0, stream>>>(
        vectors, senders, receivers, offs, rank, epackA, epackB,
        node_feats, W0_up, W1_up, ubf, xpk, E, N, FPB);

    if (use_split) {
        mlp_kernel<<<768, 256, 0, stream>>>(
            epackA, W1B, Wm2B, W3B, wmix, E, 768 * 4);
        gather_kernel<<<(N + 3) / 4, 256, 0, stream>>>(
            epackB, offs, ubf, wmix, acc, N);
    } else {
        edge_kernel<<<512, 256, 0, stream>>>(
            epackA, epackB, offs, ubf, W1B, Wm2B, W3B, acc, N, 512 * 4);
    }

    int ngroups = (N + 15) / 16;
    node_out_kernel<<<(ngroups + 3) / 4, 256, 0, stream>>>(
        acc, xpk, node_specie, WoB, out, N);
}

// Round 18
// 195.735 us; speedup vs baseline: 2.7603x; 1.2097x over previous
//
#include <hip/hip_runtime.h>
#include <hip/hip_bf16.h>

typedef __attribute__((ext_vector_type(8))) short short8;
typedef __attribute__((ext_vector_type(4))) float f32x4;

__device__ __forceinline__ unsigned bf16u(float x) {
    unsigned u = __float_as_uint(x);
    return (u + 0x7fffu + ((u >> 16) & 1u)) >> 16;
}
__device__ __forceinline__ short bf16s(float x) { return (short)bf16u(x); }

// ---------------------------------------------------------------------------
// Prep (merged): zero padded cnt + pack ALL weights into MFMA B-fragments.
// cnt is padded: one counter per 64B cacheline (stride 16 ints).
// ---------------------------------------------------------------------------
__global__ __launch_bounds__(256) void prep_kernel(
    const float* __restrict__ Wm1, const float* __restrict__ Wm2,
    const float* __restrict__ Wm3,
    const float* __restrict__ Wd0, const float* __restrict__ Ws0,
    const float* __restrict__ Wd1, const float* __restrict__ Ws1,
    short* __restrict__ W1B, short* __restrict__ Wm2B, short* __restrict__ W3B,
    short* __restrict__ WoB, int* __restrict__ cnt, int N)
{
    const int tid = blockIdx.x * 256 + threadIdx.x;
    const int nth = gridDim.x * 256;

    for (int i = tid; i < N * 16; i += nth) cnt[i] = 0;

    for (int idx = tid; idx < 52 * 64; idx += nth) {
        int l = idx & 63, f = idx >> 6;
        int g = l >> 4, c = l & 15;
        short8 v;
        if (f < 4) {
            #pragma unroll
            for (int i = 0; i < 8; ++i)
                v[i] = (g == 0) ? bf16s(Wm1[(size_t)i * 64 + f * 16 + c]) : (short)0;
            *(short8*)(W1B + (size_t)f * 512 + l * 8) = v;
        } else if (f < 12) {
            int f2 = f - 4, t = f2 >> 1, kh = f2 & 1;
            #pragma unroll
            for (int i = 0; i < 8; ++i)
                v[i] = bf16s(Wm2[(size_t)(kh * 32 + g * 8 + i) * 64 + t * 16 + c]);
            *(short8*)(Wm2B + (size_t)f2 * 512 + l * 8) = v;
        } else {
            int f3 = f - 12, t = f3 >> 1, kh = f3 & 1;
            #pragma unroll
            for (int i = 0; i < 8; ++i)
                v[i] = bf16s(Wm3[(size_t)(kh * 32 + g * 8 + i) * 320 + t * 16 + c]);
            *(short8*)(W3B + (size_t)f3 * 512 + l * 8) = v;
        }
    }

    for (int idx = tid; idx < 144 * 64; idx += nth) {
        int l = idx & 63, f = idx >> 6;
        int g = l >> 4, c = l & 15;
        short8 v;
        if (f < 16) {
            int t = f >> 1, kh = f & 1;
            #pragma unroll
            for (int i = 0; i < 8; ++i)
                v[i] = bf16s(Wd0[(size_t)(kh * 32 + g * 8 + i) * 128 + t * 16 + c]);
        } else if (f < 96) {
            int s = (f - 16) >> 4, r = (f - 16) & 15, t = r >> 1, kh = r & 1;
            #pragma unroll
            for (int i = 0; i < 8; ++i)
                v[i] = bf16s(Ws0[((size_t)s * 64 + kh * 32 + g * 8 + i) * 128 + t * 16 + c]);
        } else if (f < 104) {
            int r = f - 96, t = r >> 1, kh = r & 1;
            #pragma unroll
            for (int i = 0; i < 8; ++i)
                v[i] = bf16s(Wd1[(size_t)(kh * 32 + g * 8 + i) * 64 + t * 16 + c]);
        } else {
            int s = (f - 104) >> 3, r = (f - 104) & 7, t = r >> 1, kh = r & 1;
            #pragma unroll
            for (int i = 0; i < 8; ++i)
                v[i] = bf16s(Ws1[((size_t)s * 64 + kh * 32 + g * 8 + i) * 64 + t * 16 + c]);
        }
        *(short8*)(WoB + (size_t)f * 512 + l * 8) = v;
    }
}

// ---------------------------------------------------------------------------
// Rank pass: the ONLY atomic pass (padded counters, 64B apart).
// ---------------------------------------------------------------------------
__global__ __launch_bounds__(256) void rank_kernel(
    const int* __restrict__ receivers, int* __restrict__ cnt,
    int* __restrict__ rank, int E)
{
    int i = blockIdx.x * 256 + threadIdx.x;
    int stride = gridDim.x * 256;
    for (; i < E; i += stride)
        rank[i] = atomicAdd(&cnt[receivers[i] << 4], 1);
}

__global__ __launch_bounds__(256) void scan1_kernel(
    const int* __restrict__ cnt, int* __restrict__ offs,
    int* __restrict__ part, int N)
{
    __shared__ int a_[256], b_[256];
    const int b = blockIdx.x, t = threadIdx.x;
    const int base = b * 1024 + t * 4;
    int v[4];
    #pragma unroll
    for (int k = 0; k < 4; ++k)
        v[k] = (base + k < N) ? cnt[(size_t)(base + k) << 4] : 0;
    int sum = v[0] + v[1] + v[2] + v[3];
    a_[t] = sum;
    __syncthreads();
    int* src = a_; int* dst = b_;
    for (int off = 1; off < 256; off <<= 1) {
        dst[t] = src[t] + ((t >= off) ? src[t - off] : 0);
        __syncthreads();
        int* tmp = src; src = dst; dst = tmp;
    }
    int excl = src[t] - sum;
    if (t == 0) part[b] = src[255];
    int run = excl;
    #pragma unroll
    for (int k = 0; k < 4; ++k) {
        if (base + k < N) offs[base + k] = run;
        run += v[k];
    }
}

__global__ __launch_bounds__(256) void scan23_kernel(
    int* __restrict__ offs, const int* __restrict__ part, int nblk, int N)
{
    __shared__ int base_s, total_s;
    const int b = blockIdx.x, t = threadIdx.x;
    if (t == 0) {
        int s = 0, tot = 0;
        for (int i = 0; i < nblk; ++i) {
            if (i < b) s += part[i];
            tot += part[i];
        }
        base_s = s; total_s = tot;
    }
    __syncthreads();
    const int add = base_s;
    const int base = b * 1024 + t * 4;
    #pragma unroll
    for (int k = 0; k < 4; ++k) {
        int i = base + k;
        if (i < N) offs[i] += add;
    }
    if (b == 0 && t == 0) offs[N] = total_s;
}

// ---------------------------------------------------------------------------
// Merged fill_pack + node_up. Pack pass atomic-free (offs+rank).
// node_up: nf staged via ONE coalesced float4 load/lane into LDS, then
// broadcast reads — removes the 256-deep dependent scalar-load chain that
// made R17's fpnu latency-bound.
// ---------------------------------------------------------------------------
__global__ __launch_bounds__(256) void fpnu_kernel(
    const float* __restrict__ vectors, const int* __restrict__ senders,
    const int* __restrict__ receivers, const int* __restrict__ offs,
    const int* __restrict__ rank,
    uint4* __restrict__ epackA, float4* __restrict__ epackB,
    const float* __restrict__ node_feats, const float* __restrict__ W0_up,
    const float* __restrict__ W1_up, uint2* __restrict__ ubf,
    short* __restrict__ xpk, int E, int N, int FPB)
{
    __shared__ float lnf[4][256];
    if (blockIdx.x < FPB) {
        int i = blockIdx.x * 256 + threadIdx.x;
        int stride = FPB * 256;
        for (; i < E; i += stride) {
            int pos = offs[receivers[i]] + rank[i];
            float vx = vectors[3 * (size_t)i + 0];
            float vy = vectors[3 * (size_t)i + 1];
            float vz = vectors[3 * (size_t)i + 2];
            float r = sqrtf(vx * vx + vy * vy + vz * vz);
            float ir = (r != 0.f) ? 1.f / r : 0.f;
            float ang = r * 0.6283185307179586f;   // pi/5
            float s1, c1;
            __sincosf(ang, &s1, &c1);
            float tc = 2.f * c1;
            float sb = s1, sp = 0.f;
            float coef = 0.6324555320336759f * ir;
            unsigned bw[4];
            #pragma unroll
            for (int h = 0; h < 4; ++h) {
                unsigned lo = bf16u(sb * coef);
                float nx = tc * sb - sp; sp = sb; sb = nx;
                unsigned hi = bf16u(sb * coef);
                nx = tc * sb - sp; sp = sb; sb = nx;
                bw[h] = lo | (hi << 16);
            }
            epackA[pos] = make_uint4(bw[0], bw[1], bw[2], bw[3]);
            epackB[pos] = make_float4(vx * ir, vy * ir, vz * ir,
                                      __int_as_float(senders[i]));
        }
    } else {
        const int wv = threadIdx.x >> 6;
        const int d  = threadIdx.x & 63;
        int nb = (blockIdx.x - FPB) * 4 + wv;
        if (nb >= N) return;

        // stage node feats: one coalesced float4 per lane -> LDS
        float4 v4 = *(const float4*)(node_feats + (size_t)nb * 256 + d * 4);
        *(float4*)&lnf[wv][d * 4] = v4;
        // per-wave buffer: compiler inserts lgkmcnt before first ds_read

        float a0 = 0.f, ax = 0.f, ay = 0.f, az = 0.f;
        #pragma unroll 8
        for (int cc = 0; cc < 64; ++cc) {
            float w0 = W0_up[cc * 64 + d];     // coalesced, L1/L2-hit
            float w1 = W1_up[cc * 64 + d];
            float x0v = lnf[wv][cc];            // LDS broadcast
            float xxv = lnf[wv][64 + cc * 3 + 0];
            float xyv = lnf[wv][64 + cc * 3 + 1];
            float xzv = lnf[wv][64 + cc * 3 + 2];
            a0 += x0v * w0;
            ax += xxv * w1;
            ay += xyv * w1;
            az += xzv * w1;
        }
        ubf[(size_t)nb * 64 + d] = make_uint2(bf16u(a0) | (bf16u(ax) << 16),
                                              bf16u(ay) | (bf16u(az) << 16));
        short* xp = xpk + (size_t)nb * 256;
        xp[d]       = bf16s(lnf[wv][d]);
        xp[64 + d]  = bf16s(lnf[wv][64 + d * 3 + 0]);
        xp[128 + d] = bf16s(lnf[wv][64 + d * 3 + 1]);
        xp[192 + d] = bf16s(lnf[wv][64 + d * 3 + 2]);
    }
}

// ---------------------------------------------------------------------------
// SPLIT kernel A: dense MLP over flat 16-row CSR windows -> wmix bf16.
// ---------------------------------------------------------------------------
__global__ __launch_bounds__(256) void mlp_kernel(
    const uint4* __restrict__ epackA,
    const short* __restrict__ W1B, const short* __restrict__ Wm2B,
    const short* __restrict__ W3B, unsigned short* __restrict__ wmix,
    int P, int nwaves)
{
    __shared__ __align__(16) short ldsW3[40 * 512];
    __shared__ __align__(16) short ldsH[4][1024];

    {
        const short8* src = (const short8*)W3B;
        short8* dst = (short8*)ldsW3;
        for (int i = threadIdx.x; i < 2560; i += 256) dst[i] = src[i];
    }
    __syncthreads();

    const int lane = threadIdx.x & 63;
    const int wv   = threadIdx.x >> 6;
    const int gw   = blockIdx.x * 4 + wv;
    const int c = lane & 15, g = lane >> 4;
    const int nwin = (P + 15) >> 4;

    for (int w = gw; w < nwin; w += nwaves) {
        const int p0 = w << 4;

        short8 basisA = {0, 0, 0, 0, 0, 0, 0, 0};
        if (lane < 16) {
            uint4 ba = epackA[p0 + lane];
            union { uint4 u4v; short8 s8; } cv;
            cv.u4v = ba;
            basisA = cv.s8;
        }

        #pragma unroll
        for (int t = 0; t < 4; ++t) {
            f32x4 h = {0.f, 0.f, 0.f, 0.f};
            short8 bf = *(const short8*)(W1B + (size_t)t * 512 + lane * 8);
            h = __builtin_amdgcn_mfma_f32_16x16x32_bf16(basisA, bf, h, 0, 0, 0);
            #pragma unroll
            for (int i = 0; i < 4; ++i) {
                float x = h[i];
                float h1 = x / (1.f + __expf(-x));
                int row = 4 * g + i;
                ldsH[wv][row * 64 + ((16 * t + c) ^ ((row & 7) << 3))] = bf16s(h1);
            }
        }
        short8 h1f0 = *(const short8*)&ldsH[wv][c * 64 + ((g * 8) ^ ((c & 7) << 3))];
        short8 h1f1 = *(const short8*)&ldsH[wv][c * 64 + ((32 + g * 8) ^ ((c & 7) << 3))];

        #pragma unroll
        for (int t = 0; t < 4; ++t) {
            f32x4 h = {0.f, 0.f, 0.f, 0.f};
            short8 b0 = *(const short8*)(Wm2B + (size_t)(t * 2) * 512 + lane * 8);
            short8 b1 = *(const short8*)(Wm2B + (size_t)(t * 2 + 1) * 512 + lane * 8);
            h = __builtin_amdgcn_mfma_f32_16x16x32_bf16(h1f0, b0, h, 0, 0, 0);
            h = __builtin_amdgcn_mfma_f32_16x16x32_bf16(h1f1, b1, h, 0, 0, 0);
            #pragma unroll
            for (int i = 0; i < 4; ++i) {
                float x = h[i];
                float h2 = x / (1.f + __expf(-x));
                int row = 4 * g + i;
                ldsH[wv][row * 64 + ((16 * t + c) ^ ((row & 7) << 3))] = bf16s(h2);
            }
        }
        short8 h2f0 = *(const short8*)&ldsH[wv][c * 64 + ((g * 8) ^ ((c & 7) << 3))];
        short8 h2f1 = *(const short8*)&ldsH[wv][c * 64 + ((32 + g * 8) ^ ((c & 7) << 3))];

        size_t rowOfs[4];
        bool ok[4];
        #pragma unroll
        for (int i = 0; i < 4; ++i) {
            int row = p0 + 4 * g + i;
            ok[i] = (row < P);
            rowOfs[i] = (size_t)row * 320;
        }
        #pragma unroll
        for (int t = 0; t < 20; ++t) {
            f32x4 wq = {0.f, 0.f, 0.f, 0.f};
            short8 b0 = *(const short8*)(ldsW3 + (size_t)(t * 2) * 512 + lane * 8);
            short8 b1 = *(const short8*)(ldsW3 + (size_t)(t * 2 + 1) * 512 + lane * 8);
            wq = __builtin_amdgcn_mfma_f32_16x16x32_bf16(h2f0, b0, wq, 0, 0, 0);
            wq = __builtin_amdgcn_mfma_f32_16x16x32_bf16(h2f1, b1, wq, 0, 0, 0);
            const int col = (t >> 2) * 64 + (t & 3) * 16 + c;
            #pragma unroll
            for (int i = 0; i < 4; ++i)
                if (ok[i]) wmix[rowOfs[i] + col] = (unsigned short)bf16u(wq[i]);
        }
    }
}

// ---------------------------------------------------------------------------
// SPLIT kernel B: gather + messages + accumulate. Wave per node, lane=d.
// ---------------------------------------------------------------------------
__global__ __launch_bounds__(256) void gather_kernel(
    const float4* __restrict__ epackB, const int* __restrict__ offs,
    const uint2* __restrict__ ubf, const unsigned short* __restrict__ wmix,
    float* __restrict__ acc, int N)
{
    const int lane = threadIdx.x & 63;
    const int n = blockIdx.x * 4 + (threadIdx.x >> 6);
    if (n >= N) return;

    const int beg = offs[n], end = offs[n + 1];
    float a0 = 0.f, a1x = 0.f, a1y = 0.f, a1z = 0.f;

    #pragma unroll 2
    for (int pos = beg; pos < end; ++pos) {
        float4 mb = epackB[pos];
        int snd = __float_as_int(mb.w);
        uint2 mu = ubf[(size_t)snd * 64 + lane];
        const unsigned short* wr = wmix + (size_t)pos * 320;
        float w00  = __uint_as_float((unsigned)wr[lane]        << 16);
        float w01  = __uint_as_float((unsigned)wr[64 + lane]   << 16);
        float w10  = __uint_as_float((unsigned)wr[128 + lane]  << 16);
        float w11d = __uint_as_float((unsigned)wr[192 + lane]  << 16);
        float w11c = __uint_as_float((unsigned)wr[256 + lane]  << 16);
        float m0  = __uint_as_float(mu.x << 16);
        float m1x = __uint_as_float(mu.x & 0xffff0000u);
        float m1y = __uint_as_float(mu.y << 16);
        float m1z = __uint_as_float(mu.y & 0xffff0000u);

        float dotv = m1x * mb.x + m1y * mb.y + m1z * mb.z;
        a0 += w00 * m0 + w11d * dotv;
        float wm = w01 * m0;
        a1x += wm * mb.x + w10 * m1x + w11c * (m1y * mb.z - m1z * mb.y);
        a1y += wm * mb.y + w10 * m1y + w11c * (m1z * mb.x - m1x * mb.z);
        a1z += wm * mb.z + w10 * m1z + w11c * (m1x * mb.y - m1y * mb.x);
    }

    float* ar = acc + (size_t)n * 256;
    ar[lane]       = a0;
    ar[64 + lane]  = a1x;
    ar[128 + lane] = a1y;
    ar[192 + lane] = a1z;
}

// ---------------------------------------------------------------------------
// FALLBACK: fused edge kernel (R13 version; used when ws too small for wmix)
// ---------------------------------------------------------------------------
__global__ __launch_bounds__(256) void edge_kernel(
    const uint4* __restrict__ epackA, const float4* __restrict__ epackB,
    const int* __restrict__ offs, const uint2* __restrict__ ubf,
    const short* __restrict__ W1B, const short* __restrict__ Wm2B,
    const short* __restrict__ W3B, float* __restrict__ acc,
    int N, int nwaves)
{
    __shared__ __align__(16) short ldsW3[40 * 512];
    __shared__ __align__(16) short ldsH[4][1024];
    __shared__ __align__(16) float ldsMeta[4][16][4];

    {
        const short8* src = (const short8*)W3B;
        short8* dst = (short8*)ldsW3;
        for (int i = threadIdx.x; i < 2560; i += 256) dst[i] = src[i];
    }
    __syncthreads();

    const int lane = threadIdx.x & 63;
    const int wv   = threadIdx.x >> 6;
    const int gw   = blockIdx.x * 4 + wv;
    const int c = lane & 15, g = lane >> 4;

    for (int n = gw; n < N; n += nwaves) {
        float a0q[4]  = {0.f, 0.f, 0.f, 0.f};
        float a1xq[4] = {0.f, 0.f, 0.f, 0.f};
        float a1yq[4] = {0.f, 0.f, 0.f, 0.f};
        float a1zq[4] = {0.f, 0.f, 0.f, 0.f};
        const int beg = offs[n], end = offs[n + 1];

        for (int p0 = beg; p0 < end; p0 += 16) {
            const int m = end - p0;
            short8 basisA = {0, 0, 0, 0, 0, 0, 0, 0};
            if (lane < 16) {
                uint4 ba = epackA[p0 + lane];
                float4 mb = epackB[p0 + lane];
                if (lane >= m) {
                    ba = make_uint4(0u, 0u, 0u, 0u);
                    mb = make_float4(0.f, 0.f, 0.f, __int_as_float(0));
                }
                union { uint4 u4v; short8 s8; } cv;
                cv.u4v = ba;
                basisA = cv.s8;
                *(float4*)&ldsMeta[wv][lane][0] = mb;
            }
            float Yx[4], Yy[4], Yz[4];
            int snd[4];
            #pragma unroll
            for (int i = 0; i < 4; ++i) {
                float4 mt = *(const float4*)&ldsMeta[wv][4 * g + i][0];
                Yx[i] = mt.x; Yy[i] = mt.y; Yz[i] = mt.z;
                snd[i] = __float_as_int(mt.w);
            }

#define PFETCH(Q, MV)                                                       \
            _Pragma("unroll")                                               \
            for (int i = 0; i < 4; ++i)                                     \
                MV[i] = ubf[(size_t)snd[i] * 64 + 16 * (Q) + c];

#define COMPQ(Q, MV)                                                        \
        {                                                                   \
            float M0[4], M1X[4], M1Y[4], M1Z[4];                            \
            _Pragma("unroll")                                               \
            for (int i = 0; i < 4; ++i) {                                   \
                M0[i]  = __uint_as_float(MV[i].x << 16);                    \
                M1X[i] = __uint_as_float(MV[i].x & 0xffff0000u);            \
                M1Y[i] = __uint_as_float(MV[i].y << 16);                    \
                M1Z[i] = __uint_as_float(MV[i].y & 0xffff0000u);            \
            }                                                               \
            _Pragma("unroll")                                               \
            for (int p = 0; p < 5; ++p) {                                   \
                const int t = 4 * p + (Q);                                  \
                f32x4 w = {0.f, 0.f, 0.f, 0.f};                             \
                short8 b0 = *(const short8*)(ldsW3 + (size_t)(t * 2) * 512 + lane * 8);     \
                short8 b1 = *(const short8*)(ldsW3 + (size_t)(t * 2 + 1) * 512 + lane * 8); \
                w = __builtin_amdgcn_mfma_f32_16x16x32_bf16(h2f0, b0, w, 0, 0, 0);          \
                w = __builtin_amdgcn_mfma_f32_16x16x32_bf16(h2f1, b1, w, 0, 0, 0);          \
                _Pragma("unroll")                                           \
                for (int i = 0; i < 4; ++i) {                               \
                    float wv_ = w[i];                                       \
                    if (p == 0) {                                           \
                        a0q[Q] += wv_ * M0[i];                              \
                    } else if (p == 1) {                                    \
                        float tt = wv_ * M0[i];                             \
                        a1xq[Q] += tt * Yx[i];                              \
                        a1yq[Q] += tt * Yy[i];                              \
                        a1zq[Q] += tt * Yz[i];                              \
                    } else if (p == 2) {                                    \
                        a1xq[Q] += wv_ * M1X[i];                            \
                        a1yq[Q] += wv_ * M1Y[i];                            \
                        a1zq[Q] += wv_ * M1Z[i];                            \
                    } else if (p == 3) {                                    \
                        a0q[Q] += wv_ * (M1X[i] * Yx[i] + M1Y[i] * Yy[i] + M1Z[i] * Yz[i]); \
                    } else {                                                \
                        a1xq[Q] += wv_ * (M1Y[i] * Yz[i] - M1Z[i] * Yy[i]); \
                        a1yq[Q] += wv_ * (M1Z[i] * Yx[i] - M1X[i] * Yz[i]); \
                        a1zq[Q] += wv_ * (M1X[i] * Yy[i] - M1Y[i] * Yx[i]); \
                    }                                                       \
                }                                                           \
            }                                                               \
        }

            uint2 mA[4], mB[4];
            PFETCH(0, mA);
            PFETCH(1, mB);
            __builtin_amdgcn_sched_barrier(0);

            #pragma unroll
            for (int t = 0; t < 4; ++t) {
                f32x4 h = {0.f, 0.f, 0.f, 0.f};
                short8 bf = *(const short8*)(W1B + (size_t)t * 512 + lane * 8);
                h = __builtin_amdgcn_mfma_f32_16x16x32_bf16(basisA, bf, h, 0, 0, 0);
                #pragma unroll
                for (int i = 0; i < 4; ++i) {
                    float x = h[i];
                    float h1 = x / (1.f + __expf(-x));
                    int row = 4 * g + i;
                    ldsH[wv][row * 64 + ((16 * t + c) ^ ((row & 7) << 3))] = bf16s(h1);
                }
            }
            short8 h1f0 = *(const short8*)&ldsH[wv][c * 64 + ((g * 8) ^ ((c & 7) << 3))];
            short8 h1f1 = *(const short8*)&ldsH[wv][c * 64 + ((32 + g * 8) ^ ((c & 7) << 3))];

            #pragma unroll
            for (int t = 0; t < 4; ++t) {
                f32x4 h = {0.f, 0.f, 0.f, 0.f};
                short8 b0 = *(const short8*)(Wm2B + (size_t)(t * 2) * 512 + lane * 8);
                short8 b1 = *(const short8*)(Wm2B + (size_t)(t * 2 + 1) * 512 + lane * 8);
                h = __builtin_amdgcn_mfma_f32_16x16x32_bf16(h1f0, b0, h, 0, 0, 0);
                h = __builtin_amdgcn_mfma_f32_16x16x32_bf16(h1f1, b1, h, 0, 0, 0);
                #pragma unroll
                for (int i = 0; i < 4; ++i) {
                    float x = h[i];
                    float h2 = x / (1.f + __expf(-x));
                    int row = 4 * g + i;
                    ldsH[wv][row * 64 + ((16 * t + c) ^ ((row & 7) << 3))] = bf16s(h2);
                }
            }
            short8 h2f0 = *(const short8*)&ldsH[wv][c * 64 + ((g * 8) ^ ((c & 7) << 3))];
            short8 h2f1 = *(const short8*)&ldsH[wv][c * 64 + ((32 + g * 8) ^ ((c & 7) << 3))];

            COMPQ(0, mA);
            __builtin_amdgcn_sched_barrier(0);
            PFETCH(2, mA);
            COMPQ(1, mB);
            __builtin_amdgcn_sched_barrier(0);
            PFETCH(3, mB);
            COMPQ(2, mA);
            __builtin_amdgcn_sched_barrier(0);
            COMPQ(3, mB);
#undef PFETCH
#undef COMPQ
        }

        #pragma unroll
        for (int q = 0; q < 4; ++q) {
            a0q[q]  += __shfl_xor(a0q[q], 16);  a0q[q]  += __shfl_xor(a0q[q], 32);
            a1xq[q] += __shfl_xor(a1xq[q], 16); a1xq[q] += __shfl_xor(a1xq[q], 32);
            a1yq[q] += __shfl_xor(a1yq[q], 16); a1yq[q] += __shfl_xor(a1yq[q], 32);
            a1zq[q] += __shfl_xor(a1zq[q], 16); a1zq[q] += __shfl_xor(a1zq[q], 32);
        }
        if (lane < 16) {
            float* ar = acc + (size_t)n * 256;
            #pragma unroll
            for (int q = 0; q < 4; ++q) {
                ar[16 * q + lane]       = a0q[q];
                ar[64 + 16 * q + lane]  = a1xq[q];
                ar[128 + 16 * q + lane] = a1yq[q];
                ar[192 + 16 * q + lane] = a1zq[q];
            }
        }
    }
}

// ---------------------------------------------------------------------------
// Node epilogue: MFMA masked-species dense GEMM. (unchanged)
// ---------------------------------------------------------------------------
__global__ __launch_bounds__(256) void node_out_kernel(
    const float* __restrict__ acc, const short* __restrict__ xpk,
    const int* __restrict__ node_specie, const short* __restrict__ WoB,
    float* __restrict__ out, int N)
{
    __shared__ float ldsOut[4][16][256];
    const int lane = threadIdx.x & 63;
    const int wv   = threadIdx.x >> 6;
    const int c = lane & 15, g = lane >> 4;
    const int n0 = (blockIdx.x * 4 + wv) * 16;
    if (n0 >= N) return;

    const int nc = min(n0 + c, N - 1);
    const int sp_c = node_specie[nc];
    const short8 z8 = {0, 0, 0, 0, 0, 0, 0, 0};

    short8 x0f[2], a0hi[2], a0lo[2];
    #pragma unroll
    for (int kh = 0; kh < 2; ++kh) {
        x0f[kh] = *(const short8*)&xpk[(size_t)nc * 256 + kh * 32 + g * 8];
        const float* ap = acc + (size_t)nc * 256 + kh * 32 + g * 8;
        #pragma unroll
        for (int i = 0; i < 8; ++i) {
            float v = 0.25f * ap[i];
            unsigned h = bf16u(v);
            a0hi[kh][i] = (short)h;
            a0lo[kh][i] = (short)bf16u(v - __uint_as_float(h << 16));
        }
    }

    f32x4 w0[8];
    #pragma unroll
    for (int t = 0; t < 8; ++t) w0[t] = (f32x4){0.f, 0.f, 0.f, 0.f};
    #pragma unroll
    for (int t = 0; t < 8; ++t)
        #pragma unroll
        for (int kh = 0; kh < 2; ++kh) {
            short8 b = *(const short8*)(WoB + (size_t)(t * 2 + kh) * 512 + lane * 8);
            w0[t] = __builtin_amdgcn_mfma_f32_16x16x32_bf16(a0hi[kh], b, w0[t], 0, 0, 0);
            w0[t] = __builtin_amdgcn_mfma_f32_16x16x32_bf16(a0lo[kh], b, w0[t], 0, 0, 0);
        }
    #pragma unroll
    for (int s = 0; s < 5; ++s) {
        if (!__any(sp_c == s)) continue;
        short8 mk0 = (sp_c == s) ? x0f[0] : z8;
        short8 mk1 = (sp_c == s) ? x0f[1] : z8;
        #pragma unroll
        for (int t = 0; t < 8; ++t) {
            short8 b0 = *(const short8*)(WoB + (size_t)(16 + s * 16 + t * 2) * 512 + lane * 8);
            short8 b1 = *(const short8*)(WoB + (size_t)(16 + s * 16 + t * 2 + 1) * 512 + lane * 8);
            w0[t] = __builtin_amdgcn_mfma_f32_16x16x32_bf16(mk0, b0, w0[t], 0, 0, 0);
            w0[t] = __builtin_amdgcn_mfma_f32_16x16x32_bf16(mk1, b1, w0[t], 0, 0, 0);
        }
    }
    float gate[4][4];
    #pragma unroll
    for (int t = 0; t < 8; ++t)
        #pragma unroll
        for (int i = 0; i < 4; ++i) {
            float x = w0[t][i];
            float sv = x / (1.f + __expf(-x));
            if (t < 4) ldsOut[wv][4 * g + i][16 * t + c] = sv;
            else       gate[t - 4][i] = sv;
        }

    short8 x1f[3][2], a1hi[3][2], a1lo[3][2];
    #pragma unroll
    for (int j = 0; j < 3; ++j)
        #pragma unroll
        for (int kh = 0; kh < 2; ++kh) {
            x1f[j][kh] = *(const short8*)&xpk[(size_t)nc * 256 + (1 + j) * 64 + kh * 32 + g * 8];
            const float* ap = acc + (size_t)nc * 256 + 64 + 64 * j + kh * 32 + g * 8;
            #pragma unroll
            for (int i = 0; i < 8; ++i) {
                float v = 0.25f * ap[i];
                unsigned h = bf16u(v);
                a1hi[j][kh][i] = (short)h;
                a1lo[j][kh][i] = (short)bf16u(v - __uint_as_float(h << 16));
            }
        }

    f32x4 w1[3][4];
    #pragma unroll
    for (int j = 0; j < 3; ++j)
        #pragma unroll
        for (int t = 0; t < 4; ++t) w1[j][t] = (f32x4){0.f, 0.f, 0.f, 0.f};
    #pragma unroll
    for (int t = 0; t < 4; ++t)
        #pragma unroll
        for (int kh = 0; kh < 2; ++kh) {
            short8 b = *(const short8*)(WoB + (size_t)(96 + t * 2 + kh) * 512 + lane * 8);
            #pragma unroll
            for (int j = 0; j < 3; ++j) {
                w1[j][t] = __builtin_amdgcn_mfma_f32_16x16x32_bf16(a1hi[j][kh], b, w1[j][t], 0, 0, 0);
                w1[j][t] = __builtin_amdgcn_mfma_f32_16x16x32_bf16(a1lo[j][kh], b, w1[j][t], 0, 0, 0);
            }
        }
    #pragma unroll
    for (int s = 0; s < 5; ++s) {
        if (!__any(sp_c == s)) continue;
        short8 m1[3][2];
        #pragma unroll
        for (int j = 0; j < 3; ++j) {
            m1[j][0] = (sp_c == s) ? x1f[j][0] : z8;
            m1[j][1] = (sp_c == s) ? x1f[j][1] : z8;
        }
        #pragma unroll
        for (int t = 0; t < 4; ++t)
            #pragma unroll
            for (int kh = 0; kh < 2; ++kh) {
                short8 b = *(const short8*)(WoB + (size_t)(104 + s * 8 + t * 2 + kh) * 512 + lane * 8);
                #pragma unroll
                for (int j = 0; j < 3; ++j)
                    w1[j][t] = __builtin_amdgcn_mfma_f32_16x16x32_bf16(m1[j][kh], b, w1[j][t], 0, 0, 0);
            }
    }
    #pragma unroll
    for (int j = 0; j < 3; ++j)
        #pragma unroll
        for (int t = 0; t < 4; ++t)
            #pragma unroll
            for (int i = 0; i < 4; ++i)
                ldsOut[wv][4 * g + i][64 + (16 * t + c) * 3 + j] = w1[j][t][i] * gate[t][i];

    #pragma unroll 4
    for (int r = 0; r < 16; ++r) {
        int nn = n0 + r;
        if (nn < N)
            *(float4*)&out[(size_t)nn * 256 + lane * 4] =
                *(const float4*)&ldsOut[wv][r][lane * 4];
    }
}

// ---------------------------------------------------------------------------
extern "C" void kernel_launch(void* const* d_in, const int* in_sizes, int n_in,
                              void* d_out, int out_size, void* d_ws, size_t ws_size,
                              hipStream_t stream) {
    const float* vectors     = (const float*)d_in[0];
    const float* node_feats  = (const float*)d_in[1];
    const int*   node_specie = (const int*)d_in[2];
    const int*   senders     = (const int*)d_in[3];
    const int*   receivers   = (const int*)d_in[4];
    const float* W0_up       = (const float*)d_in[5];
    const float* W1_up       = (const float*)d_in[6];
    const float* Wm1         = (const float*)d_in[7];
    const float* Wm2         = (const float*)d_in[8];
    const float* Wm3         = (const float*)d_in[9];
    const float* Ws0         = (const float*)d_in[10];
    const float* Ws1         = (const float*)d_in[11];
    const float* Wd0         = (const float*)d_in[12];
    const float* Wd1         = (const float*)d_in[13];
    float* out = (float*)d_out;

    int E = in_sizes[0] / 3;
    int N = in_sizes[1] / 256;
    int nblk = (N + 1023) / 1024;

    char* wp = (char*)d_ws;
    uint2* ubf     = (uint2*)wp;                wp += (size_t)N * 64 * 8;
    float* acc     = (float*)wp;                wp += (size_t)N * 256 * 4;
    short* xpk     = (short*)wp;                wp += (size_t)N * 256 * 2;
    uint4* epackA  = (uint4*)wp;                wp += (size_t)(E + 16) * 16;
    float4* epackB = (float4*)wp;               wp += (size_t)(E + 16) * 16;
    unsigned short* wmix = (unsigned short*)wp; // only used on split path
    size_t wmix_bytes = (size_t)(E + 16) * 320 * 2;
    size_t base_used = (size_t)(wp - (char*)d_ws);
    size_t other_bytes = (4 + 8 + 40 + 144) * 512 * 2
                       + (size_t)N * 16 * 4
                       + (size_t)(N + 1) * 4
                       + (size_t)E * 4
                       + (size_t)(nblk + 1) * 4 + 256;
    bool use_split = (base_used + wmix_bytes + other_bytes) <= ws_size;
    if (use_split) wp += wmix_bytes;

    short* W1B    = (short*)wp;                 wp += 4 * 512 * 2;
    short* Wm2B   = (short*)wp;                 wp += 8 * 512 * 2;
    short* W3B    = (short*)wp;                 wp += 40 * 512 * 2;
    short* WoB    = (short*)wp;                 wp += 144 * 512 * 2;
    int*   cnt    = (int*)wp;                   wp += (size_t)N * 16 * 4;
    int*   offs   = (int*)wp;                   wp += (size_t)(N + 1) * 4;
    int*   rank   = (int*)wp;                   wp += (size_t)E * 4;
    int*   part   = (int*)wp;                   wp += (size_t)(nblk + 1) * 4;

    prep_kernel<<<80, 256, 0, stream>>>(
        Wm1, Wm2, Wm3, Wd0, Ws0, Wd1, Ws1, W1B, Wm2B, W3B, WoB, cnt, N);
    rank_kernel<<<1024, 256, 0, stream>>>(receivers, cnt, rank, E);
    scan1_kernel<<<nblk, 256, 0, stream>>>(cnt, offs, part, N);
    scan23_kernel<<<nblk, 256, 0, stream>>>(offs, part, nblk, N);
    const int FPB = 1024;
    fpnu_kernel<<<FPB + (N + 3) / 4, 256, 0, stream>>>(
        vectors, senders, receivers, offs, rank, epackA, epackB,
        node_feats, W0_up, W1_up, ubf, xpk, E, N, FPB);

    if (use_split) {
        mlp_kernel<<<768, 256, 0, stream>>>(
            epackA, W1B, Wm2B, W3B, wmix, E, 768 * 4);
        gather_kernel<<<(N + 3) / 4, 256, 0, stream>>>(
            epackB, offs, ubf, wmix, acc, N);
    } else {
        edge_kernel<<<512, 256, 0, stream>>>(
            epackA, epackB, offs, ubf, W1B, Wm2B, W3B, acc, N, 512 * 4);
    }

    int ngroups = (N + 15) / 16;
    node_out_kernel<<<(ngroups + 3) / 4, 256, 0, stream>>>(
        acc, xpk, node_specie, WoB, out, N);
}